// Round 1
// baseline (1763.389 us; speedup 1.0000x reference)
//
#include <hip/hip_runtime.h>

typedef __attribute__((ext_vector_type(8))) __bf16 bf16x8;
typedef __attribute__((ext_vector_type(4))) float f32x4;

__device__ inline bf16x8 pack8(f32x4 u0, f32x4 u1) {
    bf16x8 r;
    r[0] = (__bf16)u0[0]; r[1] = (__bf16)u0[1]; r[2] = (__bf16)u0[2]; r[3] = (__bf16)u0[3];
    r[4] = (__bf16)u1[0]; r[5] = (__bf16)u1[1]; r[6] = (__bf16)u1[2]; r[7] = (__bf16)u1[3];
    return r;
}

// ---- W [384][128] f32 -> WT [128][384] bf16 ----
__global__ void wt_convert(const float* __restrict__ W, __bf16* __restrict__ WT) {
    int i = blockIdx.x * blockDim.x + threadIdx.x;   // i = k*128 + d
    if (i >= 384 * 128) return;
    int k = i >> 7, d = i & 127;
    WT[d * 384 + k] = (__bf16)W[i];
}

// ---- scatter-add: dst[idx[e]] += src[e] (rowwise, D=128) ----
__global__ void scatter_add_kernel(const float4* __restrict__ src, const int* __restrict__ idx,
                                   float* __restrict__ dst, int E) {
    long total = (long)E * 32;
    long stride = (long)gridDim.x * blockDim.x;
    for (long i = (long)blockIdx.x * blockDim.x + threadIdx.x; i < total; i += stride) {
        long e = i >> 5; int c = (int)(i & 31);
        float4 v = src[i];
        int t = idx[e];
        float* d = dst + (long)t * 128 + c * 4;
        atomicAdd(d + 0, v.x); atomicAdd(d + 1, v.y);
        atomicAdd(d + 2, v.z); atomicAdd(d + 3, v.w);
    }
}

// ---- o = a + b (elementwise float4) ----
__global__ void add_kernel(const float4* __restrict__ a, const float4* __restrict__ b,
                           float4* __restrict__ o, long n4) {
    long stride = (long)gridDim.x * blockDim.x;
    for (long i = (long)blockIdx.x * blockDim.x + threadIdx.x; i < n4; i += stride) {
        float4 x = a[i], y = b[i];
        o[i] = make_float4(x.x + y.x, x.y + y.y, x.z + y.z, x.w + y.w);
    }
}

// ---- fused gather + MLP (relu(H @ W + b)) + optional scatter ----
// H[e] = concat(xtab[idx[e]], sumtab[idx[e]] - prev[e], eattr[e])  [384]
// PHASE 1: prev = prev_m (f32), out -> m1 (bf16), scatter-add into scat[idx2[e]]
// PHASE 2: prev = m1 (bf16), out -> outf (f32)
template <int PHASE>
__global__ __launch_bounds__(256) void mlp_kernel(
    const float* __restrict__ xtab, const float* __restrict__ sumtab,
    const float* __restrict__ prevf, const __bf16* __restrict__ prevb,
    const float* __restrict__ eattr, const int* __restrict__ idx,
    const int* __restrict__ idx2, const __bf16* __restrict__ WT,
    const float* __restrict__ bias, __bf16* __restrict__ outb,
    float* __restrict__ outf, float* __restrict__ scat, int E) {
    const int wave = threadIdx.x >> 6;
    const int lane = threadIdx.x & 63;
    const int row = lane & 15;   // A-fragment row within 16
    const int kch = lane >> 4;   // k-chunk 0..3 (8 bf16 each)
    const long wbase = ((long)blockIdx.x * 4 + wave) * 32;

    // Build A fragments for 2 row-tiles x 12 k-steps, held across the whole n-loop.
    bf16x8 a[2][12];
#pragma unroll
    for (int rb = 0; rb < 2; ++rb) {
        long e = wbase + rb * 16 + row;
        long el = (e < E) ? e : 0;        // clamp; garbage rows never stored
        int g = idx[el];
        const float* xrow = xtab + (long)g * 128 + kch * 8;
        const float* srow = sumtab + (long)g * 128 + kch * 8;
        const float* erow = eattr + el * 128 + kch * 8;
#pragma unroll
        for (int t = 0; t < 4; ++t) {     // k in [0,128): x part
            f32x4 u0 = *(const f32x4*)(xrow + t * 32);
            f32x4 u1 = *(const f32x4*)(xrow + t * 32 + 4);
            a[rb][t] = pack8(u0, u1);
        }
        if (PHASE == 1) {
            const float* prow = prevf + el * 128 + kch * 8;
#pragma unroll
            for (int t = 0; t < 4; ++t) { // k in [128,256): y = sum - prev
                f32x4 s0 = *(const f32x4*)(srow + t * 32);
                f32x4 s1 = *(const f32x4*)(srow + t * 32 + 4);
                f32x4 p0 = *(const f32x4*)(prow + t * 32);
                f32x4 p1 = *(const f32x4*)(prow + t * 32 + 4);
                a[rb][4 + t] = pack8(s0 - p0, s1 - p1);
            }
        } else {
            const __bf16* prow = prevb + el * 128 + kch * 8;
#pragma unroll
            for (int t = 0; t < 4; ++t) {
                f32x4 s0 = *(const f32x4*)(srow + t * 32);
                f32x4 s1 = *(const f32x4*)(srow + t * 32 + 4);
                bf16x8 m = *(const bf16x8*)(prow + t * 32);
                f32x4 m0, m1v;
                m0[0] = (float)m[0]; m0[1] = (float)m[1]; m0[2] = (float)m[2]; m0[3] = (float)m[3];
                m1v[0] = (float)m[4]; m1v[1] = (float)m[5]; m1v[2] = (float)m[6]; m1v[3] = (float)m[7];
                a[rb][4 + t] = pack8(s0 - m0, s1 - m1v);
            }
        }
#pragma unroll
        for (int t = 0; t < 4; ++t) {     // k in [256,384): edge_attr
            f32x4 u0 = *(const f32x4*)(erow + t * 32);
            f32x4 u1 = *(const f32x4*)(erow + t * 32 + 4);
            a[rb][8 + t] = pack8(u0, u1);
        }
    }

    const int colbase = lane & 15;
    const int orow = (lane >> 4) * 4;     // D-row base for this lane's 4 acc regs

    int f_r[2][4];
    if (PHASE == 1) {
#pragma unroll
        for (int rb = 0; rb < 2; ++rb)
#pragma unroll
            for (int r = 0; r < 4; ++r) {
                long eo = wbase + rb * 16 + orow + r;
                f_r[rb][r] = idx2[(eo < E) ? eo : 0];
            }
    }

    for (int n = 0; n < 8; ++n) {
        int col = n * 16 + colbase;
        const __bf16* wcol = WT + (long)col * 384 + kch * 8;
        f32x4 acc[2];
        acc[0] = (f32x4){0.f, 0.f, 0.f, 0.f};
        acc[1] = (f32x4){0.f, 0.f, 0.f, 0.f};
#pragma unroll
        for (int t = 0; t < 12; ++t) {
            bf16x8 b = *(const bf16x8*)(wcol + t * 32);
            acc[0] = __builtin_amdgcn_mfma_f32_16x16x32_bf16(a[0][t], b, acc[0], 0, 0, 0);
            acc[1] = __builtin_amdgcn_mfma_f32_16x16x32_bf16(a[1][t], b, acc[1], 0, 0, 0);
        }
        float bz = bias[col];
#pragma unroll
        for (int rb = 0; rb < 2; ++rb) {
#pragma unroll
            for (int r = 0; r < 4; ++r) {
                long eo = wbase + rb * 16 + orow + r;
                if (eo < E) {
                    float v = acc[rb][r] + bz;
                    v = v > 0.f ? v : 0.f;
                    if (PHASE == 1) {
                        outb[eo * 128 + col] = (__bf16)v;
                        atomicAdd(scat + (long)f_r[rb][r] * 128 + col, v);
                    } else {
                        outf[eo * 128 + col] = v;
                    }
                }
            }
        }
    }
}

extern "C" void kernel_launch(void* const* d_in, const int* in_sizes, int n_in,
                              void* d_out, int out_size, void* d_ws, size_t ws_size,
                              hipStream_t stream) {
    const float* prev_m   = (const float*)d_in[0];
    const float* variable = (const float*)d_in[1];
    const float* factor   = (const float*)d_in[2];
    const float* eattr    = (const float*)d_in[3];
    const int*   v_to_f   = (const int*)d_in[4];
    const int*   f_to_v   = (const int*)d_in[5];
    const float* Wv       = (const float*)d_in[6];
    const float* bv       = (const float*)d_in[7];
    const float* Wf       = (const float*)d_in[8];
    const float* bf       = (const float*)d_in[9];

    const int E = in_sizes[0] / 128;
    const int V = in_sizes[1] / 128;
    const int F = in_sizes[2] / 128;

    float* out_m        = (float*)d_out;               // [E,128]
    float* out_factor   = out_m + (long)E * 128;       // [F,128]
    float* out_variable = out_factor + (long)F * 128;  // [V,128]

    char* ws = (char*)d_ws;
    float* sum_f_to_v = (float*)ws;  ws += (long)V * 128 * 4;
    float* sum_v_to_f = (float*)ws;  ws += (long)F * 128 * 4;
    __bf16* m1        = (__bf16*)ws; ws += (long)E * 128 * 2;
    __bf16* WvT       = (__bf16*)ws; ws += 384 * 128 * 2;
    __bf16* WfT       = (__bf16*)ws;

    hipMemsetAsync(sum_f_to_v, 0, (size_t)V * 128 * 4, stream);
    hipMemsetAsync(sum_v_to_f, 0, (size_t)F * 128 * 4, stream);

    wt_convert<<<dim3(192), dim3(256), 0, stream>>>(Wv, WvT);
    wt_convert<<<dim3(192), dim3(256), 0, stream>>>(Wf, WfT);

    scatter_add_kernel<<<dim3(4096), dim3(256), 0, stream>>>(
        (const float4*)prev_m, v_to_f, sum_f_to_v, E);

    int blocks = (E + 127) / 128;  // 128 edges per block (4 waves x 32 rows)
    mlp_kernel<1><<<dim3(blocks), dim3(256), 0, stream>>>(
        variable, sum_f_to_v, prev_m, nullptr, eattr, v_to_f, f_to_v,
        WvT, bv, m1, nullptr, sum_v_to_f, E);
    mlp_kernel<2><<<dim3(blocks), dim3(256), 0, stream>>>(
        factor, sum_v_to_f, nullptr, m1, eattr, f_to_v, nullptr,
        WfT, bf, nullptr, out_m, nullptr, E);

    add_kernel<<<dim3(2048), dim3(256), 0, stream>>>(
        (const float4*)sum_v_to_f, (const float4*)factor, (float4*)out_factor, (long)F * 32);
    add_kernel<<<dim3(2048), dim3(256), 0, stream>>>(
        (const float4*)sum_f_to_v, (const float4*)variable, (float4*)out_variable, (long)V * 32);
}

// Round 2
// 1010.575 us; speedup vs baseline: 1.7449x; 1.7449x over previous
//
#include <hip/hip_runtime.h>

typedef __attribute__((ext_vector_type(8))) __bf16 bf16x8;
typedef __attribute__((ext_vector_type(2))) __bf16 bf16x2;
typedef __attribute__((ext_vector_type(4))) float f32x4;

__device__ inline bf16x8 pack8(f32x4 u0, f32x4 u1) {
    bf16x8 r;
    r[0] = (__bf16)u0[0]; r[1] = (__bf16)u0[1]; r[2] = (__bf16)u0[2]; r[3] = (__bf16)u0[3];
    r[4] = (__bf16)u1[0]; r[5] = (__bf16)u1[1]; r[6] = (__bf16)u1[2]; r[7] = (__bf16)u1[3];
    return r;
}

// ---- W [384][128] f32 -> WT [128][384] bf16 ----
__global__ void wt_convert(const float* __restrict__ W, __bf16* __restrict__ WT) {
    int i = blockIdx.x * blockDim.x + threadIdx.x;   // i = k*128 + d
    if (i >= 384 * 128) return;
    int k = i >> 7, d = i & 127;
    WT[d * 384 + k] = (__bf16)W[i];
}

// ================= CSR build (counts -> scan -> fill) =================

__global__ void hist_kernel(const int* __restrict__ v_to_f, const int* __restrict__ f_to_v,
                            int* __restrict__ counts, int V, int E) {
    int stride = gridDim.x * blockDim.x;
    for (int e = blockIdx.x * blockDim.x + threadIdx.x; e < E; e += stride) {
        atomicAdd(&counts[v_to_f[e]], 1);
        atomicAdd(&counts[V + f_to_v[e]], 1);
    }
}

#define SCAN_BLOCK 256
#define SCAN_ELEMS 4   // 1024 elements per block

__global__ void scan_pass1(const int* __restrict__ counts, int* __restrict__ partials, int N) {
    int t = threadIdx.x;
    int base = blockIdx.x * (SCAN_BLOCK * SCAN_ELEMS) + t * SCAN_ELEMS;
    int s = 0;
#pragma unroll
    for (int j = 0; j < SCAN_ELEMS; ++j) {
        int i = base + j;
        if (i < N) s += counts[i];
    }
#pragma unroll
    for (int off = 1; off < 64; off <<= 1) s += __shfl_xor(s, off);
    __shared__ int lds[4];
    if ((t & 63) == 0) lds[t >> 6] = s;
    __syncthreads();
    if (t == 0) partials[blockIdx.x] = lds[0] + lds[1] + lds[2] + lds[3];
}

__global__ void scan_pass2(int* __restrict__ partials, int nb, int* __restrict__ offsets,
                           int N, int total) {
    int t = threadIdx.x;
    int v = (t < nb) ? partials[t] : 0;
    int lane = t & 63, w = t >> 6;
    int x = v;
#pragma unroll
    for (int off = 1; off < 64; off <<= 1) { int y = __shfl_up(x, off); if (lane >= off) x += y; }
    __shared__ int lds[4];
    if (lane == 63) lds[w] = x;
    __syncthreads();
    int add = 0;
    for (int i = 0; i < w; ++i) add += lds[i];
    if (t < nb) partials[t] = x + add - v;   // exclusive
    if (t == 0) offsets[N] = total;
}

__global__ void scan_pass3(const int* __restrict__ counts, const int* __restrict__ partials,
                           int* __restrict__ offsets, int* __restrict__ cursors, int N) {
    int t = threadIdx.x;
    int base = blockIdx.x * (SCAN_BLOCK * SCAN_ELEMS) + t * SCAN_ELEMS;
    int c[SCAN_ELEMS];
    int s = 0;
#pragma unroll
    for (int j = 0; j < SCAN_ELEMS; ++j) {
        int i = base + j;
        c[j] = (i < N) ? counts[i] : 0;
        s += c[j];
    }
    int lane = t & 63, w = t >> 6;
    int x = s;
#pragma unroll
    for (int off = 1; off < 64; off <<= 1) { int y = __shfl_up(x, off); if (lane >= off) x += y; }
    __shared__ int lds[4];
    if (lane == 63) lds[w] = x;
    __syncthreads();
    int add = 0;
    for (int i = 0; i < w; ++i) add += lds[i];
    int run = x + add - s + partials[blockIdx.x];
#pragma unroll
    for (int j = 0; j < SCAN_ELEMS; ++j) {
        int i = base + j;
        if (i < N) { offsets[i] = run; cursors[i] = run; }
        run += c[j];
    }
}

__global__ void fill_kernel(const int* __restrict__ v_to_f, const int* __restrict__ f_to_v,
                            int* __restrict__ cursors, int* __restrict__ bucket, int V, int E) {
    int stride = gridDim.x * blockDim.x;
    for (int e = blockIdx.x * blockDim.x + threadIdx.x; e < E; e += stride) {
        int p = atomicAdd(&cursors[v_to_f[e]], 1);
        bucket[p] = e;
        int q = atomicAdd(&cursors[V + f_to_v[e]], 1);
        bucket[q] = e;
    }
}

// ================= gather-sum (segment sum, no atomics) =================
// one wave per target row; lane owns cols [2*lane, 2*lane+1]
// fused: addout = sum + addtab   (new_variable / new_factor)

__global__ __launch_bounds__(256) void gsum_f32(
    const float* __restrict__ src, const int* __restrict__ bucket,
    const int* __restrict__ offsets, int toff,
    const float* __restrict__ addtab, float* __restrict__ sumout,
    float* __restrict__ addout, int T) {
    int gw = (int)((blockIdx.x * (long)blockDim.x + threadIdx.x) >> 6);
    if (gw >= T) return;
    int lane = threadIdx.x & 63;
    int start = offsets[toff + gw], end = offsets[toff + gw + 1];
    float ax = 0.f, ay = 0.f;
    for (int i = start; i < end; ++i) {
        int e = bucket[i];
        float2 v = *(const float2*)(src + (long)e * 128 + lane * 2);
        ax += v.x; ay += v.y;
    }
    long o = (long)gw * 128 + lane * 2;
    *(float2*)(sumout + o) = make_float2(ax, ay);
    float2 a = *(const float2*)(addtab + o);
    *(float2*)(addout + o) = make_float2(ax + a.x, ay + a.y);
}

__global__ __launch_bounds__(256) void gsum_bf16(
    const __bf16* __restrict__ src, const int* __restrict__ bucket,
    const int* __restrict__ offsets, int toff,
    const float* __restrict__ addtab, float* __restrict__ sumout,
    float* __restrict__ addout, int T) {
    int gw = (int)((blockIdx.x * (long)blockDim.x + threadIdx.x) >> 6);
    if (gw >= T) return;
    int lane = threadIdx.x & 63;
    int start = offsets[toff + gw], end = offsets[toff + gw + 1];
    float ax = 0.f, ay = 0.f;
    for (int i = start; i < end; ++i) {
        int e = bucket[i];
        bf16x2 v = *(const bf16x2*)(src + (long)e * 128 + lane * 2);
        ax += (float)v[0]; ay += (float)v[1];
    }
    long o = (long)gw * 128 + lane * 2;
    *(float2*)(sumout + o) = make_float2(ax, ay);
    float2 a = *(const float2*)(addtab + o);
    *(float2*)(addout + o) = make_float2(ax + a.x, ay + a.y);
}

// ================= fused gather + MLP (relu(H @ W + b)) =================
// H[e] = concat(xtab[idx[e]], sumtab[idx[e]] - prev[e], eattr[e])  [384]
// PHASE 1: prev = prev_m (f32), out -> outb (bf16)
// PHASE 2: prev = m1 (bf16),   out -> outf (f32)
template <int PHASE>
__global__ __launch_bounds__(256) void mlp_kernel(
    const float* __restrict__ xtab, const float* __restrict__ sumtab,
    const float* __restrict__ prevf, const __bf16* __restrict__ prevb,
    const float* __restrict__ eattr, const int* __restrict__ idx,
    const __bf16* __restrict__ WT, const float* __restrict__ bias,
    __bf16* __restrict__ outb, float* __restrict__ outf, int E) {
    const int wave = threadIdx.x >> 6;
    const int lane = threadIdx.x & 63;
    const int row = lane & 15;   // A-fragment row within 16
    const int kch = lane >> 4;   // k-chunk 0..3 (8 bf16 each)
    const long wbase = ((long)blockIdx.x * 4 + wave) * 32;

    // Build A fragments for 2 row-tiles x 12 k-steps, held across the whole n-loop.
    bf16x8 a[2][12];
#pragma unroll
    for (int rb = 0; rb < 2; ++rb) {
        long e = wbase + rb * 16 + row;
        long el = (e < E) ? e : 0;        // clamp; garbage rows never stored
        int g = idx[el];
        const float* xrow = xtab + (long)g * 128 + kch * 8;
        const float* srow = sumtab + (long)g * 128 + kch * 8;
        const float* erow = eattr + el * 128 + kch * 8;
#pragma unroll
        for (int t = 0; t < 4; ++t) {     // k in [0,128): x part
            f32x4 u0 = *(const f32x4*)(xrow + t * 32);
            f32x4 u1 = *(const f32x4*)(xrow + t * 32 + 4);
            a[rb][t] = pack8(u0, u1);
        }
        if (PHASE == 1) {
            const float* prow = prevf + el * 128 + kch * 8;
#pragma unroll
            for (int t = 0; t < 4; ++t) { // k in [128,256): y = sum - prev
                f32x4 s0 = *(const f32x4*)(srow + t * 32);
                f32x4 s1 = *(const f32x4*)(srow + t * 32 + 4);
                f32x4 p0 = *(const f32x4*)(prow + t * 32);
                f32x4 p1 = *(const f32x4*)(prow + t * 32 + 4);
                a[rb][4 + t] = pack8(s0 - p0, s1 - p1);
            }
        } else {
            const __bf16* prow = prevb + el * 128 + kch * 8;
#pragma unroll
            for (int t = 0; t < 4; ++t) {
                f32x4 s0 = *(const f32x4*)(srow + t * 32);
                f32x4 s1 = *(const f32x4*)(srow + t * 32 + 4);
                bf16x8 m = *(const bf16x8*)(prow + t * 32);
                f32x4 m0, m1v;
                m0[0] = (float)m[0]; m0[1] = (float)m[1]; m0[2] = (float)m[2]; m0[3] = (float)m[3];
                m1v[0] = (float)m[4]; m1v[1] = (float)m[5]; m1v[2] = (float)m[6]; m1v[3] = (float)m[7];
                a[rb][4 + t] = pack8(s0 - m0, s1 - m1v);
            }
        }
#pragma unroll
        for (int t = 0; t < 4; ++t) {     // k in [256,384): edge_attr
            f32x4 u0 = *(const f32x4*)(erow + t * 32);
            f32x4 u1 = *(const f32x4*)(erow + t * 32 + 4);
            a[rb][8 + t] = pack8(u0, u1);
        }
    }

    const int colbase = lane & 15;
    const int orow = (lane >> 4) * 4;     // D-row base for this lane's 4 acc regs

    for (int n = 0; n < 8; ++n) {
        int col = n * 16 + colbase;
        const __bf16* wcol = WT + (long)col * 384 + kch * 8;
        f32x4 acc[2];
        acc[0] = (f32x4){0.f, 0.f, 0.f, 0.f};
        acc[1] = (f32x4){0.f, 0.f, 0.f, 0.f};
#pragma unroll
        for (int t = 0; t < 12; ++t) {
            bf16x8 b = *(const bf16x8*)(wcol + t * 32);
            acc[0] = __builtin_amdgcn_mfma_f32_16x16x32_bf16(a[0][t], b, acc[0], 0, 0, 0);
            acc[1] = __builtin_amdgcn_mfma_f32_16x16x32_bf16(a[1][t], b, acc[1], 0, 0, 0);
        }
        float bz = bias[col];
#pragma unroll
        for (int rb = 0; rb < 2; ++rb) {
#pragma unroll
            for (int r = 0; r < 4; ++r) {
                long eo = wbase + rb * 16 + orow + r;
                if (eo < E) {
                    float v = acc[rb][r] + bz;
                    v = v > 0.f ? v : 0.f;
                    if (PHASE == 1) outb[eo * 128 + col] = (__bf16)v;
                    else            outf[eo * 128 + col] = v;
                }
            }
        }
    }
}

extern "C" void kernel_launch(void* const* d_in, const int* in_sizes, int n_in,
                              void* d_out, int out_size, void* d_ws, size_t ws_size,
                              hipStream_t stream) {
    const float* prev_m   = (const float*)d_in[0];
    const float* variable = (const float*)d_in[1];
    const float* factor   = (const float*)d_in[2];
    const float* eattr    = (const float*)d_in[3];
    const int*   v_to_f   = (const int*)d_in[4];
    const int*   f_to_v   = (const int*)d_in[5];
    const float* Wv       = (const float*)d_in[6];
    const float* bv       = (const float*)d_in[7];
    const float* Wf       = (const float*)d_in[8];
    const float* bf       = (const float*)d_in[9];

    const int E = in_sizes[0] / 128;
    const int V = in_sizes[1] / 128;
    const int F = in_sizes[2] / 128;
    const int NT = V + F;

    float* out_m        = (float*)d_out;               // [E,128]
    float* out_factor   = out_m + (long)E * 128;       // [F,128]
    float* out_variable = out_factor + (long)F * 128;  // [V,128]

    char* ws = (char*)d_ws;
    float* sum_f_to_v = (float*)ws;  ws += (long)V * 128 * 4;
    float* sum_v_to_f = (float*)ws;  ws += (long)F * 128 * 4;
    __bf16* m1        = (__bf16*)ws; ws += (long)E * 128 * 2;
    __bf16* WvT       = (__bf16*)ws; ws += 384 * 128 * 2;
    __bf16* WfT       = (__bf16*)ws; ws += 384 * 128 * 2;
    int* counts       = (int*)ws;    ws += (long)NT * 4;
    int* offsets      = (int*)ws;    ws += (long)(NT + 1) * 4;
    int* cursors      = (int*)ws;    ws += (long)NT * 4;
    int* bucket       = (int*)ws;    ws += (long)2 * E * 4;
    int* partials     = (int*)ws;    ws += 256 * 4;

    hipMemsetAsync(counts, 0, (size_t)NT * 4, stream);

    wt_convert<<<dim3(192), dim3(256), 0, stream>>>(Wv, WvT);
    wt_convert<<<dim3(192), dim3(256), 0, stream>>>(Wf, WfT);

    // ---- CSR build ----
    hist_kernel<<<dim3(2048), dim3(256), 0, stream>>>(v_to_f, f_to_v, counts, V, E);
    int nb = (NT + SCAN_BLOCK * SCAN_ELEMS - 1) / (SCAN_BLOCK * SCAN_ELEMS);  // 147 <= 256
    scan_pass1<<<dim3(nb), dim3(SCAN_BLOCK), 0, stream>>>(counts, partials, NT);
    scan_pass2<<<dim3(1), dim3(SCAN_BLOCK), 0, stream>>>(partials, nb, offsets, NT, 2 * E);
    scan_pass3<<<dim3(nb), dim3(SCAN_BLOCK), 0, stream>>>(counts, partials, offsets, cursors, NT);
    fill_kernel<<<dim3(2048), dim3(256), 0, stream>>>(v_to_f, f_to_v, cursors, bucket, V, E);

    // ---- sum_f_to_v = segsum(prev_m, v_to_f); new_variable = sum + variable ----
    gsum_f32<<<dim3((V + 3) / 4), dim3(256), 0, stream>>>(
        prev_m, bucket, offsets, 0, variable, sum_f_to_v, out_variable, V);

    // ---- MLP1: m1 = relu([var[v], sum-prev, eattr] @ Wv + bv) (bf16) ----
    int blocks = (E + 127) / 128;  // 128 edges per block (4 waves x 32 rows)
    mlp_kernel<1><<<dim3(blocks), dim3(256), 0, stream>>>(
        variable, sum_f_to_v, prev_m, nullptr, eattr, v_to_f,
        WvT, bv, m1, nullptr, E);

    // ---- sum_v_to_f = segsum(m1, f_to_v); new_factor = sum + factor ----
    gsum_bf16<<<dim3((F + 3) / 4), dim3(256), 0, stream>>>(
        m1, bucket, offsets, V, factor, sum_v_to_f, out_factor, F);

    // ---- MLP2: out_m = relu([factor[f], sum-m1, eattr] @ Wf + bf) (f32) ----
    mlp_kernel<2><<<dim3(blocks), dim3(256), 0, stream>>>(
        factor, sum_v_to_f, nullptr, m1, eattr, f_to_v,
        WfT, bf, nullptr, out_m, E);
}

// Round 3
// 904.442 us; speedup vs baseline: 1.9497x; 1.1173x over previous
//
#include <hip/hip_runtime.h>

typedef __attribute__((ext_vector_type(8))) __bf16 bf16x8;
typedef __attribute__((ext_vector_type(2))) __bf16 bf16x2;
typedef __attribute__((ext_vector_type(4))) float f32x4;

__device__ inline bf16x8 pack8(f32x4 u0, f32x4 u1) {
    bf16x8 r;
    r[0] = (__bf16)u0[0]; r[1] = (__bf16)u0[1]; r[2] = (__bf16)u0[2]; r[3] = (__bf16)u0[3];
    r[4] = (__bf16)u1[0]; r[5] = (__bf16)u1[1]; r[6] = (__bf16)u1[2]; r[7] = (__bf16)u1[3];
    return r;
}

// ---- W [384][128] f32 -> WT2 packed in MFMA B-fragment order ----
// WT2[((t*8+n)*64 + lane)*8 + j] = W[k][col],  col = n*16+(lane&15),
//   k = t*32 + ((lane>>4)&3)*8 + j
__global__ void wt_convert(const float* __restrict__ W, __bf16* __restrict__ WT2) {
    int i = blockIdx.x * blockDim.x + threadIdx.x;   // i = k*128 + d
    if (i >= 384 * 128) return;
    int k = i >> 7, d = i & 127;
    int t = k >> 5, n = d >> 4;
    int lane = (d & 15) | (((k >> 3) & 3) << 4);
    int j = k & 7;
    WT2[((t * 8 + n) * 64 + lane) * 8 + j] = (__bf16)W[i];
}

// ================= CSR build (counts -> scan -> fill) =================

__global__ void hist_kernel(const int* __restrict__ v_to_f, const int* __restrict__ f_to_v,
                            int* __restrict__ counts, int V, int E) {
    int stride = gridDim.x * blockDim.x;
    for (int e = blockIdx.x * blockDim.x + threadIdx.x; e < E; e += stride) {
        atomicAdd(&counts[v_to_f[e]], 1);
        atomicAdd(&counts[V + f_to_v[e]], 1);
    }
}

#define SCAN_BLOCK 256
#define SCAN_ELEMS 4   // 1024 elements per block

__global__ void scan_pass1(const int* __restrict__ counts, int* __restrict__ partials, int N) {
    int t = threadIdx.x;
    int base = blockIdx.x * (SCAN_BLOCK * SCAN_ELEMS) + t * SCAN_ELEMS;
    int s = 0;
#pragma unroll
    for (int j = 0; j < SCAN_ELEMS; ++j) {
        int i = base + j;
        if (i < N) s += counts[i];
    }
#pragma unroll
    for (int off = 1; off < 64; off <<= 1) s += __shfl_xor(s, off);
    __shared__ int lds[4];
    if ((t & 63) == 0) lds[t >> 6] = s;
    __syncthreads();
    if (t == 0) partials[blockIdx.x] = lds[0] + lds[1] + lds[2] + lds[3];
}

__global__ void scan_pass2(int* __restrict__ partials, int nb, int* __restrict__ offsets,
                           int N, int total) {
    int t = threadIdx.x;
    int v = (t < nb) ? partials[t] : 0;
    int lane = t & 63, w = t >> 6;
    int x = v;
#pragma unroll
    for (int off = 1; off < 64; off <<= 1) { int y = __shfl_up(x, off); if (lane >= off) x += y; }
    __shared__ int lds[4];
    if (lane == 63) lds[w] = x;
    __syncthreads();
    int add = 0;
    for (int i = 0; i < w; ++i) add += lds[i];
    if (t < nb) partials[t] = x + add - v;   // exclusive
    if (t == 0) offsets[N] = total;
}

__global__ void scan_pass3(const int* __restrict__ counts, const int* __restrict__ partials,
                           int* __restrict__ offsets, int* __restrict__ cursors, int N) {
    int t = threadIdx.x;
    int base = blockIdx.x * (SCAN_BLOCK * SCAN_ELEMS) + t * SCAN_ELEMS;
    int c[SCAN_ELEMS];
    int s = 0;
#pragma unroll
    for (int j = 0; j < SCAN_ELEMS; ++j) {
        int i = base + j;
        c[j] = (i < N) ? counts[i] : 0;
        s += c[j];
    }
    int lane = t & 63, w = t >> 6;
    int x = s;
#pragma unroll
    for (int off = 1; off < 64; off <<= 1) { int y = __shfl_up(x, off); if (lane >= off) x += y; }
    __shared__ int lds[4];
    if (lane == 63) lds[w] = x;
    __syncthreads();
    int add = 0;
    for (int i = 0; i < w; ++i) add += lds[i];
    int run = x + add - s + partials[blockIdx.x];
#pragma unroll
    for (int j = 0; j < SCAN_ELEMS; ++j) {
        int i = base + j;
        if (i < N) { offsets[i] = run; cursors[i] = run; }
        run += c[j];
    }
}

__global__ void fill_kernel(const int* __restrict__ v_to_f, const int* __restrict__ f_to_v,
                            int* __restrict__ cursors, int* __restrict__ bucket, int V, int E) {
    int stride = gridDim.x * blockDim.x;
    for (int e = blockIdx.x * blockDim.x + threadIdx.x; e < E; e += stride) {
        int p = atomicAdd(&cursors[v_to_f[e]], 1);
        bucket[p] = e;
        int q = atomicAdd(&cursors[V + f_to_v[e]], 1);
        bucket[q] = e;
    }
}

// ================= gather-sum (segment sum, no atomics) =================
// one wave per target row; lane owns cols [2*lane, 2*lane+1]; unroll-2 for MLP.
// fused: addout = sum + addtab   (new_variable / new_factor)

__global__ __launch_bounds__(256) void gsum_f32(
    const float* __restrict__ src, const int* __restrict__ bucket,
    const int* __restrict__ offsets, int toff,
    const float* __restrict__ addtab, float* __restrict__ sumout,
    float* __restrict__ addout, int T) {
    int gw = (int)((blockIdx.x * (long)blockDim.x + threadIdx.x) >> 6);
    if (gw >= T) return;
    int lane = threadIdx.x & 63;
    int start = offsets[toff + gw], end = offsets[toff + gw + 1];
    float ax = 0.f, ay = 0.f, bx = 0.f, by = 0.f;
    int i = start;
    for (; i + 1 < end; i += 2) {
        int e0 = bucket[i], e1 = bucket[i + 1];
        float2 v0 = *(const float2*)(src + (long)e0 * 128 + lane * 2);
        float2 v1 = *(const float2*)(src + (long)e1 * 128 + lane * 2);
        ax += v0.x; ay += v0.y; bx += v1.x; by += v1.y;
    }
    if (i < end) {
        int e0 = bucket[i];
        float2 v0 = *(const float2*)(src + (long)e0 * 128 + lane * 2);
        ax += v0.x; ay += v0.y;
    }
    ax += bx; ay += by;
    long o = (long)gw * 128 + lane * 2;
    *(float2*)(sumout + o) = make_float2(ax, ay);
    float2 a = *(const float2*)(addtab + o);
    *(float2*)(addout + o) = make_float2(ax + a.x, ay + a.y);
}

__global__ __launch_bounds__(256) void gsum_bf16(
    const __bf16* __restrict__ src, const int* __restrict__ bucket,
    const int* __restrict__ offsets, int toff,
    const float* __restrict__ addtab, float* __restrict__ sumout,
    float* __restrict__ addout, int T) {
    int gw = (int)((blockIdx.x * (long)blockDim.x + threadIdx.x) >> 6);
    if (gw >= T) return;
    int lane = threadIdx.x & 63;
    int start = offsets[toff + gw], end = offsets[toff + gw + 1];
    float ax = 0.f, ay = 0.f, bx = 0.f, by = 0.f;
    int i = start;
    for (; i + 1 < end; i += 2) {
        int e0 = bucket[i], e1 = bucket[i + 1];
        bf16x2 v0 = *(const bf16x2*)(src + (long)e0 * 128 + lane * 2);
        bf16x2 v1 = *(const bf16x2*)(src + (long)e1 * 128 + lane * 2);
        ax += (float)v0[0]; ay += (float)v0[1];
        bx += (float)v1[0]; by += (float)v1[1];
    }
    if (i < end) {
        int e0 = bucket[i];
        bf16x2 v0 = *(const bf16x2*)(src + (long)e0 * 128 + lane * 2);
        ax += (float)v0[0]; ay += (float)v0[1];
    }
    ax += bx; ay += by;
    long o = (long)gw * 128 + lane * 2;
    *(float2*)(sumout + o) = make_float2(ax, ay);
    float2 a = *(const float2*)(addtab + o);
    *(float2*)(addout + o) = make_float2(ax + a.x, ay + a.y);
}

// ================= fused gather + MLP (relu(H @ W + b)) =================
// H[e] = concat(xtab[idx[e]], sumtab[idx[e]] - prev[e], eattr[e])  [384]
// Loop order: t outer (A built per k-step, 8 VGPR live), n inner (acc[8][2]).
// PHASE 1: prev = prev_m (f32), out -> outb (bf16)
// PHASE 2: prev = m1 (bf16),   out -> outf (f32)
template <int PHASE>
__global__ __launch_bounds__(256, 4) void mlp_kernel(
    const float* __restrict__ xtab, const float* __restrict__ sumtab,
    const float* __restrict__ prevf, const __bf16* __restrict__ prevb,
    const float* __restrict__ eattr, const int* __restrict__ idx,
    const __bf16* __restrict__ WT2, const float* __restrict__ bias,
    __bf16* __restrict__ outb, float* __restrict__ outf, int E) {
    const int wave = threadIdx.x >> 6;
    const int lane = threadIdx.x & 63;
    const int row = lane & 15;   // A-fragment row within 16
    const int kch = lane >> 4;   // k-chunk 0..3 (8 bf16 each)
    const long wbase = ((long)blockIdx.x * 4 + wave) * 32;

    // Per-rb source row pointers (each lane covers 8 floats at kch*8 per 32-k step)
    const float* xrow[2]; const float* srow[2]; const float* erow[2];
    const float* prowf[2]; const __bf16* prowb[2];
#pragma unroll
    for (int rb = 0; rb < 2; ++rb) {
        long e = wbase + rb * 16 + row;
        long el = (e < E) ? e : 0;        // clamp; garbage rows never stored
        int g = idx[el];
        xrow[rb] = xtab + (long)g * 128 + kch * 8;
        srow[rb] = sumtab + (long)g * 128 + kch * 8;
        erow[rb] = eattr + el * 128 + kch * 8;
        if (PHASE == 1) prowf[rb] = prevf + el * 128 + kch * 8;
        else            prowb[rb] = prevb + el * 128 + kch * 8;
    }

    f32x4 acc[8][2];
#pragma unroll
    for (int n = 0; n < 8; ++n) {
        acc[n][0] = (f32x4){0.f, 0.f, 0.f, 0.f};
        acc[n][1] = (f32x4){0.f, 0.f, 0.f, 0.f};
    }

#pragma unroll
    for (int t = 0; t < 12; ++t) {
        bf16x8 a[2];
#pragma unroll
        for (int rb = 0; rb < 2; ++rb) {
            if (t < 4) {
                f32x4 u0 = *(const f32x4*)(xrow[rb] + t * 32);
                f32x4 u1 = *(const f32x4*)(xrow[rb] + t * 32 + 4);
                a[rb] = pack8(u0, u1);
            } else if (t < 8) {
                int tt = t - 4;
                f32x4 s0 = *(const f32x4*)(srow[rb] + tt * 32);
                f32x4 s1 = *(const f32x4*)(srow[rb] + tt * 32 + 4);
                if (PHASE == 1) {
                    f32x4 p0 = *(const f32x4*)(prowf[rb] + tt * 32);
                    f32x4 p1 = *(const f32x4*)(prowf[rb] + tt * 32 + 4);
                    a[rb] = pack8(s0 - p0, s1 - p1);
                } else {
                    bf16x8 m = *(const bf16x8*)(prowb[rb] + tt * 32);
                    f32x4 m0, m1v;
                    m0[0] = (float)m[0]; m0[1] = (float)m[1]; m0[2] = (float)m[2]; m0[3] = (float)m[3];
                    m1v[0] = (float)m[4]; m1v[1] = (float)m[5]; m1v[2] = (float)m[6]; m1v[3] = (float)m[7];
                    a[rb] = pack8(s0 - m0, s1 - m1v);
                }
            } else {
                int tt = t - 8;
                f32x4 u0 = *(const f32x4*)(erow[rb] + tt * 32);
                f32x4 u1 = *(const f32x4*)(erow[rb] + tt * 32 + 4);
                a[rb] = pack8(u0, u1);
            }
        }
        // B fragments: fully coalesced 1KB wave loads, contiguous per n
        const __bf16* bbase = WT2 + ((long)t * 8) * 512 + lane * 8;
#pragma unroll
        for (int n = 0; n < 8; ++n) {
            bf16x8 b = *(const bf16x8*)(bbase + n * 512);
            acc[n][0] = __builtin_amdgcn_mfma_f32_16x16x32_bf16(a[0], b, acc[n][0], 0, 0, 0);
            acc[n][1] = __builtin_amdgcn_mfma_f32_16x16x32_bf16(a[1], b, acc[n][1], 0, 0, 0);
        }
    }

    const int colbase = lane & 15;
    const int orow = (lane >> 4) * 4;     // D-row base for this lane's 4 acc regs

#pragma unroll
    for (int n = 0; n < 8; ++n) {
        int col = n * 16 + colbase;
        float bz = bias[col];
#pragma unroll
        for (int rb = 0; rb < 2; ++rb) {
#pragma unroll
            for (int r = 0; r < 4; ++r) {
                long eo = wbase + rb * 16 + orow + r;
                if (eo < E) {
                    float v = acc[n][rb][r] + bz;
                    v = v > 0.f ? v : 0.f;
                    if (PHASE == 1) outb[eo * 128 + col] = (__bf16)v;
                    else            outf[eo * 128 + col] = v;
                }
            }
        }
    }
}

extern "C" void kernel_launch(void* const* d_in, const int* in_sizes, int n_in,
                              void* d_out, int out_size, void* d_ws, size_t ws_size,
                              hipStream_t stream) {
    const float* prev_m   = (const float*)d_in[0];
    const float* variable = (const float*)d_in[1];
    const float* factor   = (const float*)d_in[2];
    const float* eattr    = (const float*)d_in[3];
    const int*   v_to_f   = (const int*)d_in[4];
    const int*   f_to_v   = (const int*)d_in[5];
    const float* Wv       = (const float*)d_in[6];
    const float* bv       = (const float*)d_in[7];
    const float* Wf       = (const float*)d_in[8];
    const float* bf       = (const float*)d_in[9];

    const int E = in_sizes[0] / 128;
    const int V = in_sizes[1] / 128;
    const int F = in_sizes[2] / 128;
    const int NT = V + F;

    float* out_m        = (float*)d_out;               // [E,128]
    float* out_factor   = out_m + (long)E * 128;       // [F,128]
    float* out_variable = out_factor + (long)F * 128;  // [V,128]

    char* ws = (char*)d_ws;
    float* sum_f_to_v = (float*)ws;  ws += (long)V * 128 * 4;
    float* sum_v_to_f = (float*)ws;  ws += (long)F * 128 * 4;
    __bf16* m1        = (__bf16*)ws; ws += (long)E * 128 * 2;
    __bf16* WvT       = (__bf16*)ws; ws += 384 * 128 * 2;
    __bf16* WfT       = (__bf16*)ws; ws += 384 * 128 * 2;
    int* counts       = (int*)ws;    ws += (long)NT * 4;
    int* offsets      = (int*)ws;    ws += (long)(NT + 1) * 4;
    int* cursors      = (int*)ws;    ws += (long)NT * 4;
    int* bucket       = (int*)ws;    ws += (long)2 * E * 4;
    int* partials     = (int*)ws;    ws += 256 * 4;

    hipMemsetAsync(counts, 0, (size_t)NT * 4, stream);

    wt_convert<<<dim3(192), dim3(256), 0, stream>>>(Wv, WvT);
    wt_convert<<<dim3(192), dim3(256), 0, stream>>>(Wf, WfT);

    // ---- CSR build ----
    hist_kernel<<<dim3(2048), dim3(256), 0, stream>>>(v_to_f, f_to_v, counts, V, E);
    int nb = (NT + SCAN_BLOCK * SCAN_ELEMS - 1) / (SCAN_BLOCK * SCAN_ELEMS);  // 147 <= 256
    scan_pass1<<<dim3(nb), dim3(SCAN_BLOCK), 0, stream>>>(counts, partials, NT);
    scan_pass2<<<dim3(1), dim3(SCAN_BLOCK), 0, stream>>>(partials, nb, offsets, NT, 2 * E);
    scan_pass3<<<dim3(nb), dim3(SCAN_BLOCK), 0, stream>>>(counts, partials, offsets, cursors, NT);
    fill_kernel<<<dim3(2048), dim3(256), 0, stream>>>(v_to_f, f_to_v, cursors, bucket, V, E);

    // ---- sum_f_to_v = segsum(prev_m, v_to_f); new_variable = sum + variable ----
    gsum_f32<<<dim3((V + 3) / 4), dim3(256), 0, stream>>>(
        prev_m, bucket, offsets, 0, variable, sum_f_to_v, out_variable, V);

    // ---- MLP1: m1 = relu([var[v], sum-prev, eattr] @ Wv + bv) (bf16) ----
    int blocks = (E + 127) / 128;  // 128 edges per block (4 waves x 32 rows)
    mlp_kernel<1><<<dim3(blocks), dim3(256), 0, stream>>>(
        variable, sum_f_to_v, prev_m, nullptr, eattr, v_to_f,
        WvT, bv, m1, nullptr, E);

    // ---- sum_v_to_f = segsum(m1, f_to_v); new_factor = sum + factor ----
    gsum_bf16<<<dim3((F + 3) / 4), dim3(256), 0, stream>>>(
        m1, bucket, offsets, V, factor, sum_v_to_f, out_factor, F);

    // ---- MLP2: out_m = relu([factor[f], sum-m1, eattr] @ Wf + bf) (f32) ----
    mlp_kernel<2><<<dim3(blocks), dim3(256), 0, stream>>>(
        factor, sum_v_to_f, nullptr, m1, eattr, f_to_v,
        WfT, bf, nullptr, out_m, E);
}

// Round 4
// 864.091 us; speedup vs baseline: 2.0407x; 1.0467x over previous
//
#include <hip/hip_runtime.h>

typedef __attribute__((ext_vector_type(8))) __bf16 bf16x8;
typedef __attribute__((ext_vector_type(2))) __bf16 bf16x2;
typedef __attribute__((ext_vector_type(4))) float f32x4;

__device__ inline bf16x8 pack8(f32x4 u0, f32x4 u1) {
    bf16x8 r;
    r[0] = (__bf16)u0[0]; r[1] = (__bf16)u0[1]; r[2] = (__bf16)u0[2]; r[3] = (__bf16)u0[3];
    r[4] = (__bf16)u1[0]; r[5] = (__bf16)u1[1]; r[6] = (__bf16)u1[2]; r[7] = (__bf16)u1[3];
    return r;
}

// ---- pack two 128-row blocks of W (with signs) into MFMA B-fragment order ----
// K=256 (8 t-steps). out[((t*8+n)*64+lane)*8+j] = sgn*W[(base+k)*128+d],
//   col = n*16+(lane&15), k = t*32 + ((lane>>4)&3)*8 + j
__global__ void pack_w(const float* __restrict__ W, __bf16* __restrict__ out,
                       int baseA, float sA, int baseB, float sB) {
    int i = blockIdx.x * blockDim.x + threadIdx.x;
    if (i >= 256 * 128) return;
    int k = i >> 7, d = i & 127;
    float v = (k < 128) ? sA * W[(long)(baseA + k) * 128 + d]
                        : sB * W[(long)(baseB + (k - 128)) * 128 + d];
    int t = k >> 5, n = d >> 4;
    int lane = (d & 15) | (((k >> 3) & 3) << 4);
    int j = k & 7;
    out[((long)(t * 8 + n) * 64 + lane) * 8 + j] = (__bf16)v;
}

// ================= CSR build (counts -> scan -> fill) =================

__global__ void hist_kernel(const int* __restrict__ v_to_f, const int* __restrict__ f_to_v,
                            int* __restrict__ counts, int V, int E) {
    int stride = gridDim.x * blockDim.x;
    for (int e = blockIdx.x * blockDim.x + threadIdx.x; e < E; e += stride) {
        atomicAdd(&counts[v_to_f[e]], 1);
        atomicAdd(&counts[V + f_to_v[e]], 1);
    }
}

#define SCAN_BLOCK 256
#define SCAN_ELEMS 4   // 1024 elements per block

__global__ void scan_pass1(const int* __restrict__ counts, int* __restrict__ partials, int N) {
    int t = threadIdx.x;
    int base = blockIdx.x * (SCAN_BLOCK * SCAN_ELEMS) + t * SCAN_ELEMS;
    int s = 0;
#pragma unroll
    for (int j = 0; j < SCAN_ELEMS; ++j) {
        int i = base + j;
        if (i < N) s += counts[i];
    }
#pragma unroll
    for (int off = 1; off < 64; off <<= 1) s += __shfl_xor(s, off);
    __shared__ int lds[4];
    if ((t & 63) == 0) lds[t >> 6] = s;
    __syncthreads();
    if (t == 0) partials[blockIdx.x] = lds[0] + lds[1] + lds[2] + lds[3];
}

__global__ void scan_pass2(int* __restrict__ partials, int nb, int* __restrict__ offsets,
                           int N, int total) {
    int t = threadIdx.x;
    int v = (t < nb) ? partials[t] : 0;
    int lane = t & 63, w = t >> 6;
    int x = v;
#pragma unroll
    for (int off = 1; off < 64; off <<= 1) { int y = __shfl_up(x, off); if (lane >= off) x += y; }
    __shared__ int lds[4];
    if (lane == 63) lds[w] = x;
    __syncthreads();
    int add = 0;
    for (int i = 0; i < w; ++i) add += lds[i];
    if (t < nb) partials[t] = x + add - v;   // exclusive
    if (t == 0) offsets[N] = total;
}

__global__ void scan_pass3(const int* __restrict__ counts, const int* __restrict__ partials,
                           int* __restrict__ offsets, int* __restrict__ cursors, int N) {
    int t = threadIdx.x;
    int base = blockIdx.x * (SCAN_BLOCK * SCAN_ELEMS) + t * SCAN_ELEMS;
    int c[SCAN_ELEMS];
    int s = 0;
#pragma unroll
    for (int j = 0; j < SCAN_ELEMS; ++j) {
        int i = base + j;
        c[j] = (i < N) ? counts[i] : 0;
        s += c[j];
    }
    int lane = t & 63, w = t >> 6;
    int x = s;
#pragma unroll
    for (int off = 1; off < 64; off <<= 1) { int y = __shfl_up(x, off); if (lane >= off) x += y; }
    __shared__ int lds[4];
    if (lane == 63) lds[w] = x;
    __syncthreads();
    int add = 0;
    for (int i = 0; i < w; ++i) add += lds[i];
    int run = x + add - s + partials[blockIdx.x];
#pragma unroll
    for (int j = 0; j < SCAN_ELEMS; ++j) {
        int i = base + j;
        if (i < N) { offsets[i] = run; cursors[i] = run; }
        run += c[j];
    }
}

__global__ void fill_kernel(const int* __restrict__ v_to_f, const int* __restrict__ f_to_v,
                            int* __restrict__ cursors, int* __restrict__ bucket, int V, int E) {
    int stride = gridDim.x * blockDim.x;
    for (int e = blockIdx.x * blockDim.x + threadIdx.x; e < E; e += stride) {
        int p = atomicAdd(&cursors[v_to_f[e]], 1);
        bucket[p] = e;
        int q = atomicAdd(&cursors[V + f_to_v[e]], 1);
        bucket[q] = e;
    }
}

// ================= gather-sum (segment sum, no atomics) =================

__global__ __launch_bounds__(256) void gsum_f32(
    const float* __restrict__ src, const int* __restrict__ bucket,
    const int* __restrict__ offsets, int toff,
    const float* __restrict__ addtab, float* __restrict__ sumout,
    float* __restrict__ addout, int T) {
    int gw = (int)((blockIdx.x * (long)blockDim.x + threadIdx.x) >> 6);
    if (gw >= T) return;
    int lane = threadIdx.x & 63;
    int start = offsets[toff + gw], end = offsets[toff + gw + 1];
    float ax = 0.f, ay = 0.f, bx = 0.f, by = 0.f;
    int i = start;
    for (; i + 1 < end; i += 2) {
        int e0 = bucket[i], e1 = bucket[i + 1];
        float2 v0 = *(const float2*)(src + (long)e0 * 128 + lane * 2);
        float2 v1 = *(const float2*)(src + (long)e1 * 128 + lane * 2);
        ax += v0.x; ay += v0.y; bx += v1.x; by += v1.y;
    }
    if (i < end) {
        int e0 = bucket[i];
        float2 v0 = *(const float2*)(src + (long)e0 * 128 + lane * 2);
        ax += v0.x; ay += v0.y;
    }
    ax += bx; ay += by;
    long o = (long)gw * 128 + lane * 2;
    *(float2*)(sumout + o) = make_float2(ax, ay);
    float2 a = *(const float2*)(addtab + o);
    *(float2*)(addout + o) = make_float2(ax + a.x, ay + a.y);
}

__global__ __launch_bounds__(256) void gsum_bf16(
    const __bf16* __restrict__ src, const int* __restrict__ bucket,
    const int* __restrict__ offsets, int toff,
    const float* __restrict__ addtab, float* __restrict__ sumout,
    float* __restrict__ addout, int T) {
    int gw = (int)((blockIdx.x * (long)blockDim.x + threadIdx.x) >> 6);
    if (gw >= T) return;
    int lane = threadIdx.x & 63;
    int start = offsets[toff + gw], end = offsets[toff + gw + 1];
    float ax = 0.f, ay = 0.f, bx = 0.f, by = 0.f;
    int i = start;
    for (; i + 1 < end; i += 2) {
        int e0 = bucket[i], e1 = bucket[i + 1];
        bf16x2 v0 = *(const bf16x2*)(src + (long)e0 * 128 + lane * 2);
        bf16x2 v1 = *(const bf16x2*)(src + (long)e1 * 128 + lane * 2);
        ax += (float)v0[0]; ay += (float)v0[1];
        bx += (float)v1[0]; by += (float)v1[1];
    }
    if (i < end) {
        int e0 = bucket[i];
        bf16x2 v0 = *(const bf16x2*)(src + (long)e0 * 128 + lane * 2);
        ax += (float)v0[0]; ay += (float)v0[1];
    }
    ax += bx; ay += by;
    long o = (long)gw * 128 + lane * 2;
    *(float2*)(sumout + o) = make_float2(ax, ay);
    float2 a = *(const float2*)(addtab + o);
    *(float2*)(addout + o) = make_float2(ax + a.x, ay + a.y);
}

// ================= table GEMM: G[r] = src0[r]@WA + src1[r]@WB + bias =================
// contiguous rows, K=256, bf16 output, no relu
__global__ __launch_bounds__(256, 4) void table_gemm(
    const float* __restrict__ src0, const float* __restrict__ src1,
    const __bf16* __restrict__ WT, const float* __restrict__ bias,
    __bf16* __restrict__ out, int T) {
    const int wave = threadIdx.x >> 6;
    const int lane = threadIdx.x & 63;
    const int row = lane & 15;
    const int kch = lane >> 4;
    const long wbase = ((long)blockIdx.x * 4 + wave) * 32;

    const float* p0[2]; const float* p1[2];
#pragma unroll
    for (int rb = 0; rb < 2; ++rb) {
        long r = wbase + rb * 16 + row;
        long rl = (r < T) ? r : (T - 1);
        p0[rb] = src0 + rl * 128 + kch * 8;
        p1[rb] = src1 + rl * 128 + kch * 8;
    }

    f32x4 acc[8][2];
#pragma unroll
    for (int n = 0; n < 8; ++n) {
        acc[n][0] = (f32x4){0.f, 0.f, 0.f, 0.f};
        acc[n][1] = (f32x4){0.f, 0.f, 0.f, 0.f};
    }

#pragma unroll
    for (int t = 0; t < 8; ++t) {
        bf16x8 a[2];
#pragma unroll
        for (int rb = 0; rb < 2; ++rb) {
            const float* p = (t < 4) ? (p0[rb] + t * 32) : (p1[rb] + (t - 4) * 32);
            f32x4 u0 = *(const f32x4*)p;
            f32x4 u1 = *(const f32x4*)(p + 4);
            a[rb] = pack8(u0, u1);
        }
        const __bf16* bbase = WT + (long)t * 8 * 512 + lane * 8;
#pragma unroll
        for (int n = 0; n < 8; ++n) {
            bf16x8 b = *(const bf16x8*)(bbase + n * 512);
            acc[n][0] = __builtin_amdgcn_mfma_f32_16x16x32_bf16(a[0], b, acc[n][0], 0, 0, 0);
            acc[n][1] = __builtin_amdgcn_mfma_f32_16x16x32_bf16(a[1], b, acc[n][1], 0, 0, 0);
        }
    }

    const int colbase = lane & 15;
    const int orow = (lane >> 4) * 4;
#pragma unroll
    for (int n = 0; n < 8; ++n) {
        int col = n * 16 + colbase;
        float bz = bias[col];
#pragma unroll
        for (int rb = 0; rb < 2; ++rb)
#pragma unroll
            for (int rr = 0; rr < 4; ++rr) {
                long r = wbase + rb * 16 + orow + rr;
                if (r < T) out[r * 128 + col] = (__bf16)(acc[n][rb][rr] + bz);
            }
    }
}

// ================= edge GEMM: out[e] = relu(G[idx[e]] + A0[e]@WA + eattr[e]@WB) ====
// A0 = prev_m (f32, PHASE 1) or m1 (bf16, PHASE 2); all GEMM inputs streaming.
template <int PHASE>
__global__ __launch_bounds__(256, 4) void edge_gemm(
    const float* __restrict__ prevf, const __bf16* __restrict__ prevb,
    const float* __restrict__ eattr, const __bf16* __restrict__ WT,
    const __bf16* __restrict__ G, const int* __restrict__ idx,
    __bf16* __restrict__ outb, float* __restrict__ outf, int E) {
    const int wave = threadIdx.x >> 6;
    const int lane = threadIdx.x & 63;
    const int row = lane & 15;
    const int kch = lane >> 4;
    const long wbase = ((long)blockIdx.x * 4 + wave) * 32;

    const float* e0[2]; const float* pf[2]; const __bf16* pb[2];
#pragma unroll
    for (int rb = 0; rb < 2; ++rb) {
        long e = wbase + rb * 16 + row;
        long el = (e < E) ? e : (E - 1);
        e0[rb] = eattr + el * 128 + kch * 8;
        if (PHASE == 1) pf[rb] = prevf + el * 128 + kch * 8;
        else            pb[rb] = prevb + el * 128 + kch * 8;
    }

    // epilogue G-row indices: independent, issue early
    const int orow = (lane >> 4) * 4;
    int gidx[2][4];
#pragma unroll
    for (int rb = 0; rb < 2; ++rb)
#pragma unroll
        for (int rr = 0; rr < 4; ++rr) {
            long eo = wbase + rb * 16 + orow + rr;
            gidx[rb][rr] = idx[(eo < E) ? eo : (E - 1)];
        }

    f32x4 acc[8][2];
#pragma unroll
    for (int n = 0; n < 8; ++n) {
        acc[n][0] = (f32x4){0.f, 0.f, 0.f, 0.f};
        acc[n][1] = (f32x4){0.f, 0.f, 0.f, 0.f};
    }

#pragma unroll
    for (int t = 0; t < 8; ++t) {
        bf16x8 a[2];
#pragma unroll
        for (int rb = 0; rb < 2; ++rb) {
            if (t < 4) {
                if (PHASE == 1) {
                    f32x4 u0 = *(const f32x4*)(pf[rb] + t * 32);
                    f32x4 u1 = *(const f32x4*)(pf[rb] + t * 32 + 4);
                    a[rb] = pack8(u0, u1);
                } else {
                    a[rb] = *(const bf16x8*)(pb[rb] + t * 32);
                }
            } else {
                f32x4 u0 = *(const f32x4*)(e0[rb] + (t - 4) * 32);
                f32x4 u1 = *(const f32x4*)(e0[rb] + (t - 4) * 32 + 4);
                a[rb] = pack8(u0, u1);
            }
        }
        const __bf16* bbase = WT + (long)t * 8 * 512 + lane * 8;
#pragma unroll
        for (int n = 0; n < 8; ++n) {
            bf16x8 b = *(const bf16x8*)(bbase + n * 512);
            acc[n][0] = __builtin_amdgcn_mfma_f32_16x16x32_bf16(a[0], b, acc[n][0], 0, 0, 0);
            acc[n][1] = __builtin_amdgcn_mfma_f32_16x16x32_bf16(a[1], b, acc[n][1], 0, 0, 0);
        }
    }

    const int colbase = lane & 15;
#pragma unroll
    for (int n = 0; n < 8; ++n) {
        int col = n * 16 + colbase;
#pragma unroll
        for (int rb = 0; rb < 2; ++rb)
#pragma unroll
            for (int rr = 0; rr < 4; ++rr) {
                long eo = wbase + rb * 16 + orow + rr;
                if (eo < E) {
                    float v = acc[n][rb][rr] + (float)G[(long)gidx[rb][rr] * 128 + col];
                    v = v > 0.f ? v : 0.f;
                    if (PHASE == 1) outb[eo * 128 + col] = (__bf16)v;
                    else            outf[eo * 128 + col] = v;
                }
            }
    }
}

extern "C" void kernel_launch(void* const* d_in, const int* in_sizes, int n_in,
                              void* d_out, int out_size, void* d_ws, size_t ws_size,
                              hipStream_t stream) {
    const float* prev_m   = (const float*)d_in[0];
    const float* variable = (const float*)d_in[1];
    const float* factor   = (const float*)d_in[2];
    const float* eattr    = (const float*)d_in[3];
    const int*   v_to_f   = (const int*)d_in[4];
    const int*   f_to_v   = (const int*)d_in[5];
    const float* Wv       = (const float*)d_in[6];
    const float* bv       = (const float*)d_in[7];
    const float* Wf       = (const float*)d_in[8];
    const float* bf       = (const float*)d_in[9];

    const int E = in_sizes[0] / 128;
    const int V = in_sizes[1] / 128;
    const int F = in_sizes[2] / 128;
    const int NT = V + F;

    float* out_m        = (float*)d_out;               // [E,128]
    float* out_factor   = out_m + (long)E * 128;       // [F,128]
    float* out_variable = out_factor + (long)F * 128;  // [V,128]

    char* ws = (char*)d_ws;
    float* sum_f_to_v = (float*)ws;  ws += (long)V * 128 * 4;
    float* sum_v_to_f = (float*)ws;  ws += (long)F * 128 * 4;
    __bf16* m1        = (__bf16*)ws; ws += (long)E * 128 * 2;
    __bf16* G1        = (__bf16*)ws; ws += (long)V * 128 * 2;
    __bf16* G2        = (__bf16*)ws; ws += (long)F * 128 * 2;
    __bf16* Wtab_v    = (__bf16*)ws; ws += 256 * 128 * 2;
    __bf16* Wedge_v   = (__bf16*)ws; ws += 256 * 128 * 2;
    __bf16* Wtab_f    = (__bf16*)ws; ws += 256 * 128 * 2;
    __bf16* Wedge_f   = (__bf16*)ws; ws += 256 * 128 * 2;
    int* counts       = (int*)ws;    ws += (long)NT * 4;
    int* offsets      = (int*)ws;    ws += (long)(NT + 1) * 4;
    int* cursors      = (int*)ws;    ws += (long)NT * 4;
    int* bucket       = (int*)ws;    ws += (long)2 * E * 4;
    int* partials     = (int*)ws;    ws += 256 * 4;

    hipMemsetAsync(counts, 0, (size_t)NT * 4, stream);

    // weight packs: table = [W1; W2], edge = [-W2; W3]
    pack_w<<<dim3(128), dim3(256), 0, stream>>>(Wv, Wtab_v,  0,   1.f, 128, 1.f);
    pack_w<<<dim3(128), dim3(256), 0, stream>>>(Wv, Wedge_v, 128, -1.f, 256, 1.f);
    pack_w<<<dim3(128), dim3(256), 0, stream>>>(Wf, Wtab_f,  0,   1.f, 128, 1.f);
    pack_w<<<dim3(128), dim3(256), 0, stream>>>(Wf, Wedge_f, 128, -1.f, 256, 1.f);

    // ---- CSR build ----
    hist_kernel<<<dim3(2048), dim3(256), 0, stream>>>(v_to_f, f_to_v, counts, V, E);
    int nb = (NT + SCAN_BLOCK * SCAN_ELEMS - 1) / (SCAN_BLOCK * SCAN_ELEMS);  // 147 <= 256
    scan_pass1<<<dim3(nb), dim3(SCAN_BLOCK), 0, stream>>>(counts, partials, NT);
    scan_pass2<<<dim3(1), dim3(SCAN_BLOCK), 0, stream>>>(partials, nb, offsets, NT, 2 * E);
    scan_pass3<<<dim3(nb), dim3(SCAN_BLOCK), 0, stream>>>(counts, partials, offsets, cursors, NT);
    fill_kernel<<<dim3(2048), dim3(256), 0, stream>>>(v_to_f, f_to_v, cursors, bucket, V, E);

    // ---- sum_f_to_v = segsum(prev_m); new_variable = sum + variable ----
    gsum_f32<<<dim3((V + 3) / 4), dim3(256), 0, stream>>>(
        prev_m, bucket, offsets, 0, variable, sum_f_to_v, out_variable, V);

    // ---- G1[v] = var@Wv1 + sum@Wv2 + bv ----
    table_gemm<<<dim3((V + 127) / 128), dim3(256), 0, stream>>>(
        variable, sum_f_to_v, Wtab_v, bv, G1, V);

    // ---- m1 = relu(G1[v[e]] - prev@Wv2 + eattr@Wv3) ----
    int eblocks = (E + 127) / 128;
    edge_gemm<1><<<dim3(eblocks), dim3(256), 0, stream>>>(
        prev_m, nullptr, eattr, Wedge_v, G1, v_to_f, m1, nullptr, E);

    // ---- sum_v_to_f = segsum(m1); new_factor = sum + factor ----
    gsum_bf16<<<dim3((F + 3) / 4), dim3(256), 0, stream>>>(
        m1, bucket, offsets, V, factor, sum_v_to_f, out_factor, F);

    // ---- G2[f] = factor@Wf1 + sum@Wf2 + bf ----
    table_gemm<<<dim3((F + 127) / 128), dim3(256), 0, stream>>>(
        factor, sum_v_to_f, Wtab_f, bf, G2, F);

    // ---- out_m = relu(G2[f[e]] - m1@Wf2 + eattr@Wf3) ----
    edge_gemm<2><<<dim3(eblocks), dim3(256), 0, stream>>>(
        nullptr, m1, eattr, Wedge_f, G2, f_to_v, nullptr, out_m, E);
}

// Round 5
// 860.962 us; speedup vs baseline: 2.0482x; 1.0036x over previous
//
#include <hip/hip_runtime.h>

typedef __attribute__((ext_vector_type(8))) __bf16 bf16x8;
typedef __attribute__((ext_vector_type(2))) __bf16 bf16x2;
typedef __attribute__((ext_vector_type(4))) float f32x4;

__device__ __forceinline__ void gload_lds16(const void* g, void* l) {
    __builtin_amdgcn_global_load_lds(
        (const __attribute__((address_space(1))) void*)g,
        (__attribute__((address_space(3))) void*)l, 16, 0, 0);
}

__device__ inline bf16x8 pack8(f32x4 u0, f32x4 u1) {
    bf16x8 r;
    r[0] = (__bf16)u0[0]; r[1] = (__bf16)u0[1]; r[2] = (__bf16)u0[2]; r[3] = (__bf16)u0[3];
    r[4] = (__bf16)u1[0]; r[5] = (__bf16)u1[1]; r[6] = (__bf16)u1[2]; r[7] = (__bf16)u1[3];
    return r;
}

// ---- pack two 128-row blocks of W (with signs) into MFMA B-fragment order ----
// K=256 (8 t-steps). out[((t*8+n)*64+lane)*8+j] = sgn*W[(base+k)*128+d],
//   col = n*16+(lane&15), k = t*32 + ((lane>>4)&3)*8 + j
__global__ void pack_w(const float* __restrict__ W, __bf16* __restrict__ out,
                       int baseA, float sA, int baseB, float sB) {
    int i = blockIdx.x * blockDim.x + threadIdx.x;
    if (i >= 256 * 128) return;
    int k = i >> 7, d = i & 127;
    float v = (k < 128) ? sA * W[(long)(baseA + k) * 128 + d]
                        : sB * W[(long)(baseB + (k - 128)) * 128 + d];
    int t = k >> 5, n = d >> 4;
    int lane = (d & 15) | (((k >> 3) & 3) << 4);
    int j = k & 7;
    out[((long)(t * 8 + n) * 64 + lane) * 8 + j] = (__bf16)v;
}

// ================= CSR build (counts -> scan -> fill) =================

__global__ void hist_kernel(const int* __restrict__ v_to_f, const int* __restrict__ f_to_v,
                            int* __restrict__ counts, int V, int E) {
    int stride = gridDim.x * blockDim.x;
    for (int e = blockIdx.x * blockDim.x + threadIdx.x; e < E; e += stride) {
        atomicAdd(&counts[v_to_f[e]], 1);
        atomicAdd(&counts[V + f_to_v[e]], 1);
    }
}

#define SCAN_BLOCK 256
#define SCAN_ELEMS 4   // 1024 elements per block

__global__ void scan_pass1(const int* __restrict__ counts, int* __restrict__ partials, int N) {
    int t = threadIdx.x;
    int base = blockIdx.x * (SCAN_BLOCK * SCAN_ELEMS) + t * SCAN_ELEMS;
    int s = 0;
#pragma unroll
    for (int j = 0; j < SCAN_ELEMS; ++j) {
        int i = base + j;
        if (i < N) s += counts[i];
    }
#pragma unroll
    for (int off = 1; off < 64; off <<= 1) s += __shfl_xor(s, off);
    __shared__ int lds[4];
    if ((t & 63) == 0) lds[t >> 6] = s;
    __syncthreads();
    if (t == 0) partials[blockIdx.x] = lds[0] + lds[1] + lds[2] + lds[3];
}

__global__ void scan_pass2(int* __restrict__ partials, int nb, int* __restrict__ offsets,
                           int N, int total) {
    int t = threadIdx.x;
    int v = (t < nb) ? partials[t] : 0;
    int lane = t & 63, w = t >> 6;
    int x = v;
#pragma unroll
    for (int off = 1; off < 64; off <<= 1) { int y = __shfl_up(x, off); if (lane >= off) x += y; }
    __shared__ int lds[4];
    if (lane == 63) lds[w] = x;
    __syncthreads();
    int add = 0;
    for (int i = 0; i < w; ++i) add += lds[i];
    if (t < nb) partials[t] = x + add - v;   // exclusive
    if (t == 0) offsets[N] = total;
}

__global__ void scan_pass3(const int* __restrict__ counts, const int* __restrict__ partials,
                           int* __restrict__ offsets, int* __restrict__ cursors, int N) {
    int t = threadIdx.x;
    int base = blockIdx.x * (SCAN_BLOCK * SCAN_ELEMS) + t * SCAN_ELEMS;
    int c[SCAN_ELEMS];
    int s = 0;
#pragma unroll
    for (int j = 0; j < SCAN_ELEMS; ++j) {
        int i = base + j;
        c[j] = (i < N) ? counts[i] : 0;
        s += c[j];
    }
    int lane = t & 63, w = t >> 6;
    int x = s;
#pragma unroll
    for (int off = 1; off < 64; off <<= 1) { int y = __shfl_up(x, off); if (lane >= off) x += y; }
    __shared__ int lds[4];
    if (lane == 63) lds[w] = x;
    __syncthreads();
    int add = 0;
    for (int i = 0; i < w; ++i) add += lds[i];
    int run = x + add - s + partials[blockIdx.x];
#pragma unroll
    for (int j = 0; j < SCAN_ELEMS; ++j) {
        int i = base + j;
        if (i < N) { offsets[i] = run; cursors[i] = run; }
        run += c[j];
    }
}

__global__ void fill_kernel(const int* __restrict__ v_to_f, const int* __restrict__ f_to_v,
                            int* __restrict__ cursors, int* __restrict__ bucket, int V, int E) {
    int stride = gridDim.x * blockDim.x;
    for (int e = blockIdx.x * blockDim.x + threadIdx.x; e < E; e += stride) {
        int p = atomicAdd(&cursors[v_to_f[e]], 1);
        bucket[p] = e;
        int q = atomicAdd(&cursors[V + f_to_v[e]], 1);
        bucket[q] = e;
    }
}

// ================= gather-sum (segment sum, no atomics) =================

__global__ __launch_bounds__(256) void gsum_f32(
    const float* __restrict__ src, const int* __restrict__ bucket,
    const int* __restrict__ offsets, int toff,
    const float* __restrict__ addtab, float* __restrict__ sumout,
    float* __restrict__ addout, int T) {
    int gw = (int)((blockIdx.x * (long)blockDim.x + threadIdx.x) >> 6);
    if (gw >= T) return;
    int lane = threadIdx.x & 63;
    int start = offsets[toff + gw], end = offsets[toff + gw + 1];
    float ax = 0.f, ay = 0.f, bx = 0.f, by = 0.f;
    int i = start;
    for (; i + 1 < end; i += 2) {
        int e0 = bucket[i], e1 = bucket[i + 1];
        float2 v0 = *(const float2*)(src + (long)e0 * 128 + lane * 2);
        float2 v1 = *(const float2*)(src + (long)e1 * 128 + lane * 2);
        ax += v0.x; ay += v0.y; bx += v1.x; by += v1.y;
    }
    if (i < end) {
        int e0 = bucket[i];
        float2 v0 = *(const float2*)(src + (long)e0 * 128 + lane * 2);
        ax += v0.x; ay += v0.y;
    }
    ax += bx; ay += by;
    long o = (long)gw * 128 + lane * 2;
    *(float2*)(sumout + o) = make_float2(ax, ay);
    float2 a = *(const float2*)(addtab + o);
    *(float2*)(addout + o) = make_float2(ax + a.x, ay + a.y);
}

__global__ __launch_bounds__(256) void gsum_bf16(
    const __bf16* __restrict__ src, const int* __restrict__ bucket,
    const int* __restrict__ offsets, int toff,
    const float* __restrict__ addtab, float* __restrict__ sumout,
    float* __restrict__ addout, int T) {
    int gw = (int)((blockIdx.x * (long)blockDim.x + threadIdx.x) >> 6);
    if (gw >= T) return;
    int lane = threadIdx.x & 63;
    int start = offsets[toff + gw], end = offsets[toff + gw + 1];
    float ax = 0.f, ay = 0.f, bx = 0.f, by = 0.f;
    int i = start;
    for (; i + 1 < end; i += 2) {
        int e0 = bucket[i], e1 = bucket[i + 1];
        bf16x2 v0 = *(const bf16x2*)(src + (long)e0 * 128 + lane * 2);
        bf16x2 v1 = *(const bf16x2*)(src + (long)e1 * 128 + lane * 2);
        ax += (float)v0[0]; ay += (float)v0[1];
        bx += (float)v1[0]; by += (float)v1[1];
    }
    if (i < end) {
        int e0 = bucket[i];
        bf16x2 v0 = *(const bf16x2*)(src + (long)e0 * 128 + lane * 2);
        ax += (float)v0[0]; ay += (float)v0[1];
    }
    ax += bx; ay += by;
    long o = (long)gw * 128 + lane * 2;
    *(float2*)(sumout + o) = make_float2(ax, ay);
    float2 a = *(const float2*)(addtab + o);
    *(float2*)(addout + o) = make_float2(ax + a.x, ay + a.y);
}

// ================= table GEMM: G[r] = src0[r]@WA + src1[r]@WB + bias =================
// contiguous rows, K=256, bf16 output, no relu
__global__ __launch_bounds__(256, 4) void table_gemm(
    const float* __restrict__ src0, const float* __restrict__ src1,
    const __bf16* __restrict__ WT, const float* __restrict__ bias,
    __bf16* __restrict__ out, int T) {
    const int wave = threadIdx.x >> 6;
    const int lane = threadIdx.x & 63;
    const int row = lane & 15;
    const int kch = lane >> 4;
    const long wbase = ((long)blockIdx.x * 4 + wave) * 32;

    const float* p0[2]; const float* p1[2];
#pragma unroll
    for (int rb = 0; rb < 2; ++rb) {
        long r = wbase + rb * 16 + row;
        long rl = (r < T) ? r : (T - 1);
        p0[rb] = src0 + rl * 128 + kch * 8;
        p1[rb] = src1 + rl * 128 + kch * 8;
    }

    f32x4 acc[8][2];
#pragma unroll
    for (int n = 0; n < 8; ++n) {
        acc[n][0] = (f32x4){0.f, 0.f, 0.f, 0.f};
        acc[n][1] = (f32x4){0.f, 0.f, 0.f, 0.f};
    }

#pragma unroll
    for (int t = 0; t < 8; ++t) {
        bf16x8 a[2];
#pragma unroll
        for (int rb = 0; rb < 2; ++rb) {
            const float* p = (t < 4) ? (p0[rb] + t * 32) : (p1[rb] + (t - 4) * 32);
            f32x4 u0 = *(const f32x4*)p;
            f32x4 u1 = *(const f32x4*)(p + 4);
            a[rb] = pack8(u0, u1);
        }
        const __bf16* bbase = WT + (long)t * 8 * 512 + lane * 8;
#pragma unroll
        for (int n = 0; n < 8; ++n) {
            bf16x8 b = *(const bf16x8*)(bbase + n * 512);
            acc[n][0] = __builtin_amdgcn_mfma_f32_16x16x32_bf16(a[0], b, acc[n][0], 0, 0, 0);
            acc[n][1] = __builtin_amdgcn_mfma_f32_16x16x32_bf16(a[1], b, acc[n][1], 0, 0, 0);
        }
    }

    const int colbase = lane & 15;
    const int orow = (lane >> 4) * 4;
#pragma unroll
    for (int n = 0; n < 8; ++n) {
        int col = n * 16 + colbase;
        float bz = bias[col];
#pragma unroll
        for (int rb = 0; rb < 2; ++rb)
#pragma unroll
            for (int rr = 0; rr < 4; ++rr) {
                long r = wbase + rb * 16 + orow + rr;
                if (r < T) out[r * 128 + col] = (__bf16)(acc[n][rb][rr] + bz);
            }
    }
}

// ================= edge GEMM: out[e] = relu(G[idx[e]] + A0[e]@WA + eattr[e]@WB) ====
// A0 = prev_m (f32, PHASE 1) or m1 (bf16, PHASE 2).
// A-operand staged via global_load_lds (triple-buffered, XOR-swizzled source).
// Block = 128 edge rows x 128 cols; wave w owns rows [w*32, w*32+32).
template <int PHASE>
__global__ __launch_bounds__(256, 3) void edge_gemm(
    const float* __restrict__ prevf, const __bf16* __restrict__ prevb,
    const float* __restrict__ eattr, const __bf16* __restrict__ WT,
    const __bf16* __restrict__ G, const int* __restrict__ idx,
    __bf16* __restrict__ outb, float* __restrict__ outf, int E) {
    __shared__ char lds[3][16384];
    const int wave = threadIdx.x >> 6;
    const int lane = threadIdx.x & 63;
    const int row16 = lane & 15;
    const int kch = lane >> 4;
    const long brow = (long)blockIdx.x * 128;

    // stage one 32-k slice (all 128 block rows) into lds[buf]
    auto stage = [&](int buf, int t) {
        char* dst = &lds[buf][0];
        if (PHASE == 2 && t < 4) {
            // bf16 source (m1): 64B/row slice, 4 chunks of 16B, 512 slots
#pragma unroll
            for (int q = 0; q < 2; ++q) {
                int s0 = q * 256 + wave * 64;        // wave-uniform slot base
                int row = (s0 >> 2) + (lane >> 2);
                int c = lane & 3;
                int c2 = c ^ ((row >> 1) & 3);       // source-side swizzle
                long rowg = brow + row; if (rowg >= E) rowg = E - 1;
                gload_lds16(prevb + rowg * 128 + t * 32 + c2 * 8, dst + s0 * 16);
            }
        } else {
            // f32 source: 128B/row slice, 8 chunks of 16B, 1024 slots
            const float* srcb = (PHASE == 1 && t < 4) ? (prevf + t * 32)
                                                      : (eattr + (t - 4) * 32);
#pragma unroll
            for (int q = 0; q < 4; ++q) {
                int s0 = q * 256 + wave * 64;
                int row = (s0 >> 3) + (lane >> 3);
                int c = lane & 7;
                int c2 = c ^ (row & 7);
                long rowg = brow + row; if (rowg >= E) rowg = E - 1;
                gload_lds16(srcb + rowg * 128 + c2 * 4, dst + s0 * 16);
            }
        }
    };

    // epilogue G-row indices: independent, issue early
    const int orow = kch * 4;
    int gidx[2][4];
#pragma unroll
    for (int rb = 0; rb < 2; ++rb)
#pragma unroll
        for (int rr = 0; rr < 4; ++rr) {
            long eo = brow + wave * 32 + rb * 16 + orow + rr;
            gidx[rb][rr] = idx[(eo < E) ? eo : (E - 1)];
        }

    f32x4 acc[8][2];
#pragma unroll
    for (int n = 0; n < 8; ++n) {
        acc[n][0] = (f32x4){0.f, 0.f, 0.f, 0.f};
        acc[n][1] = (f32x4){0.f, 0.f, 0.f, 0.f};
    }

    stage(0, 0);
#pragma unroll
    for (int t = 0; t < 8; ++t) {
        __syncthreads();                 // drains last iter's stage (incl. vmcnt)
        if (t < 7) stage((t + 1) % 3, t + 1);  // flies during compute below
        const char* cur = &lds[t % 3][0];
        bf16x8 a[2];
#pragma unroll
        for (int rb = 0; rb < 2; ++rb) {
            int row = wave * 32 + rb * 16 + row16;
            if (PHASE == 2 && t < 4) {
                int off = row * 64 + ((kch ^ ((row >> 1) & 3)) * 16);
                a[rb] = *(const bf16x8*)(cur + off);
            } else {
                int base = row * 128;
                int s0 = (((kch * 2 + 0) ^ (row & 7)) * 16);
                int s1 = (((kch * 2 + 1) ^ (row & 7)) * 16);
                f32x4 u0 = *(const f32x4*)(cur + base + s0);
                f32x4 u1 = *(const f32x4*)(cur + base + s1);
                a[rb] = pack8(u0, u1);
            }
        }
        const __bf16* bbase = WT + (long)t * 8 * 512 + lane * 8;
#pragma unroll
        for (int n = 0; n < 8; ++n) {
            bf16x8 b = *(const bf16x8*)(bbase + n * 512);
            acc[n][0] = __builtin_amdgcn_mfma_f32_16x16x32_bf16(a[0], b, acc[n][0], 0, 0, 0);
            acc[n][1] = __builtin_amdgcn_mfma_f32_16x16x32_bf16(a[1], b, acc[n][1], 0, 0, 0);
        }
    }

    const int colbase = lane & 15;
#pragma unroll
    for (int n = 0; n < 8; ++n) {
        int col = n * 16 + colbase;
#pragma unroll
        for (int rb = 0; rb < 2; ++rb)
#pragma unroll
            for (int rr = 0; rr < 4; ++rr) {
                long eo = brow + wave * 32 + rb * 16 + orow + rr;
                if (eo < E) {
                    float v = acc[n][rb][rr] + (float)G[(long)gidx[rb][rr] * 128 + col];
                    v = v > 0.f ? v : 0.f;
                    if (PHASE == 1) outb[eo * 128 + col] = (__bf16)v;
                    else            outf[eo * 128 + col] = v;
                }
            }
    }
}

extern "C" void kernel_launch(void* const* d_in, const int* in_sizes, int n_in,
                              void* d_out, int out_size, void* d_ws, size_t ws_size,
                              hipStream_t stream) {
    const float* prev_m   = (const float*)d_in[0];
    const float* variable = (const float*)d_in[1];
    const float* factor   = (const float*)d_in[2];
    const float* eattr    = (const float*)d_in[3];
    const int*   v_to_f   = (const int*)d_in[4];
    const int*   f_to_v   = (const int*)d_in[5];
    const float* Wv       = (const float*)d_in[6];
    const float* bv       = (const float*)d_in[7];
    const float* Wf       = (const float*)d_in[8];
    const float* bf       = (const float*)d_in[9];

    const int E = in_sizes[0] / 128;
    const int V = in_sizes[1] / 128;
    const int F = in_sizes[2] / 128;
    const int NT = V + F;

    float* out_m        = (float*)d_out;               // [E,128]
    float* out_factor   = out_m + (long)E * 128;       // [F,128]
    float* out_variable = out_factor + (long)F * 128;  // [V,128]

    char* ws = (char*)d_ws;
    float* sum_f_to_v = (float*)ws;  ws += (long)V * 128 * 4;
    float* sum_v_to_f = (float*)ws;  ws += (long)F * 128 * 4;
    __bf16* m1        = (__bf16*)ws; ws += (long)E * 128 * 2;
    __bf16* G1        = (__bf16*)ws; ws += (long)V * 128 * 2;
    __bf16* G2        = (__bf16*)ws; ws += (long)F * 128 * 2;
    __bf16* Wtab_v    = (__bf16*)ws; ws += 256 * 128 * 2;
    __bf16* Wedge_v   = (__bf16*)ws; ws += 256 * 128 * 2;
    __bf16* Wtab_f    = (__bf16*)ws; ws += 256 * 128 * 2;
    __bf16* Wedge_f   = (__bf16*)ws; ws += 256 * 128 * 2;
    int* counts       = (int*)ws;    ws += (long)NT * 4;
    int* offsets      = (int*)ws;    ws += (long)(NT + 1) * 4;
    int* cursors      = (int*)ws;    ws += (long)NT * 4;
    int* bucket       = (int*)ws;    ws += (long)2 * E * 4;
    int* partials     = (int*)ws;    ws += 256 * 4;

    hipMemsetAsync(counts, 0, (size_t)NT * 4, stream);

    // weight packs: table = [W1; W2], edge = [-W2; W3]
    pack_w<<<dim3(128), dim3(256), 0, stream>>>(Wv, Wtab_v,  0,   1.f, 128, 1.f);
    pack_w<<<dim3(128), dim3(256), 0, stream>>>(Wv, Wedge_v, 128, -1.f, 256, 1.f);
    pack_w<<<dim3(128), dim3(256), 0, stream>>>(Wf, Wtab_f,  0,   1.f, 128, 1.f);
    pack_w<<<dim3(128), dim3(256), 0, stream>>>(Wf, Wedge_f, 128, -1.f, 256, 1.f);

    // ---- CSR build ----
    hist_kernel<<<dim3(2048), dim3(256), 0, stream>>>(v_to_f, f_to_v, counts, V, E);
    int nb = (NT + SCAN_BLOCK * SCAN_ELEMS - 1) / (SCAN_BLOCK * SCAN_ELEMS);  // 147 <= 256
    scan_pass1<<<dim3(nb), dim3(SCAN_BLOCK), 0, stream>>>(counts, partials, NT);
    scan_pass2<<<dim3(1), dim3(SCAN_BLOCK), 0, stream>>>(partials, nb, offsets, NT, 2 * E);
    scan_pass3<<<dim3(nb), dim3(SCAN_BLOCK), 0, stream>>>(counts, partials, offsets, cursors, NT);
    fill_kernel<<<dim3(2048), dim3(256), 0, stream>>>(v_to_f, f_to_v, cursors, bucket, V, E);

    // ---- sum_f_to_v = segsum(prev_m); new_variable = sum + variable ----
    gsum_f32<<<dim3((V + 3) / 4), dim3(256), 0, stream>>>(
        prev_m, bucket, offsets, 0, variable, sum_f_to_v, out_variable, V);

    // ---- G1[v] = var@Wv1 + sum@Wv2 + bv ----
    table_gemm<<<dim3((V + 127) / 128), dim3(256), 0, stream>>>(
        variable, sum_f_to_v, Wtab_v, bv, G1, V);

    // ---- m1 = relu(G1[v[e]] - prev@Wv2 + eattr@Wv3) ----
    int eblocks = (E + 127) / 128;
    edge_gemm<1><<<dim3(eblocks), dim3(256), 0, stream>>>(
        prev_m, nullptr, eattr, Wedge_v, G1, v_to_f, m1, nullptr, E);

    // ---- sum_v_to_f = segsum(m1); new_factor = sum + factor ----
    gsum_bf16<<<dim3((F + 3) / 4), dim3(256), 0, stream>>>(
        m1, bucket, offsets, V, factor, sum_v_to_f, out_factor, F);

    // ---- G2[f] = factor@Wf1 + sum@Wf2 + bf ----
    table_gemm<<<dim3((F + 127) / 128), dim3(256), 0, stream>>>(
        factor, sum_v_to_f, Wtab_f, bf, G2, F);

    // ---- out_m = relu(G2[f[e]] - m1@Wf2 + eattr@Wf3) ----
    edge_gemm<2><<<dim3(eblocks), dim3(256), 0, stream>>>(
        nullptr, m1, eattr, Wedge_f, G2, f_to_v, nullptr, out_m, E);
}

// Round 6
// 718.048 us; speedup vs baseline: 2.4558x; 1.1990x over previous
//
#include <hip/hip_runtime.h>

typedef __attribute__((ext_vector_type(8))) __bf16 bf16x8;
typedef __attribute__((ext_vector_type(4))) __bf16 bf16x4;
typedef __attribute__((ext_vector_type(2))) __bf16 bf16x2;
typedef __attribute__((ext_vector_type(4))) float f32x4;

__device__ __forceinline__ void gload_lds16(const void* g, void* l) {
    __builtin_amdgcn_global_load_lds(
        (const __attribute__((address_space(1))) void*)g,
        (__attribute__((address_space(3))) void*)l, 16, 0, 0);
}

__device__ inline bf16x8 pack8(f32x4 u0, f32x4 u1) {
    bf16x8 r;
    r[0] = (__bf16)u0[0]; r[1] = (__bf16)u0[1]; r[2] = (__bf16)u0[2]; r[3] = (__bf16)u0[3];
    r[4] = (__bf16)u1[0]; r[5] = (__bf16)u1[1]; r[6] = (__bf16)u1[2]; r[7] = (__bf16)u1[3];
    return r;
}

// ---- pack two 128-row blocks of W (with signs) into MFMA B-fragment order ----
// K=256 (8 t-steps). out[((t*8+n)*64+lane)*8+j] = sgn*W[(base+k)*128+d],
//   col = n*16+(lane&15), k = t*32 + ((lane>>4)&3)*8 + j
__global__ void pack_w(const float* __restrict__ W, __bf16* __restrict__ out,
                       int baseA, float sA, int baseB, float sB) {
    int i = blockIdx.x * blockDim.x + threadIdx.x;
    if (i >= 256 * 128) return;
    int k = i >> 7, d = i & 127;
    float v = (k < 128) ? sA * W[(long)(baseA + k) * 128 + d]
                        : sB * W[(long)(baseB + (k - 128)) * 128 + d];
    int t = k >> 5, n = d >> 4;
    int lane = (d & 15) | (((k >> 3) & 3) << 4);
    int j = k & 7;
    out[((long)(t * 8 + n) * 64 + lane) * 8 + j] = (__bf16)v;
}

// ================= CSR build (counts -> scan -> fill) =================

__global__ void hist_kernel(const int* __restrict__ v_to_f, const int* __restrict__ f_to_v,
                            int* __restrict__ counts, int V, int E) {
    int stride = gridDim.x * blockDim.x;
    for (int e = blockIdx.x * blockDim.x + threadIdx.x; e < E; e += stride) {
        atomicAdd(&counts[v_to_f[e]], 1);
        atomicAdd(&counts[V + f_to_v[e]], 1);
    }
}

#define SCAN_BLOCK 256
#define SCAN_ELEMS 4   // 1024 elements per block

__global__ void scan_pass1(const int* __restrict__ counts, int* __restrict__ partials, int N) {
    int t = threadIdx.x;
    int base = blockIdx.x * (SCAN_BLOCK * SCAN_ELEMS) + t * SCAN_ELEMS;
    int s = 0;
#pragma unroll
    for (int j = 0; j < SCAN_ELEMS; ++j) {
        int i = base + j;
        if (i < N) s += counts[i];
    }
#pragma unroll
    for (int off = 1; off < 64; off <<= 1) s += __shfl_xor(s, off);
    __shared__ int lds[4];
    if ((t & 63) == 0) lds[t >> 6] = s;
    __syncthreads();
    if (t == 0) partials[blockIdx.x] = lds[0] + lds[1] + lds[2] + lds[3];
}

__global__ void scan_pass2(int* __restrict__ partials, int nb, int* __restrict__ offsets,
                           int N, int total) {
    int t = threadIdx.x;
    int v = (t < nb) ? partials[t] : 0;
    int lane = t & 63, w = t >> 6;
    int x = v;
#pragma unroll
    for (int off = 1; off < 64; off <<= 1) { int y = __shfl_up(x, off); if (lane >= off) x += y; }
    __shared__ int lds[4];
    if (lane == 63) lds[w] = x;
    __syncthreads();
    int add = 0;
    for (int i = 0; i < w; ++i) add += lds[i];
    if (t < nb) partials[t] = x + add - v;   // exclusive
    if (t == 0) offsets[N] = total;
}

__global__ void scan_pass3(const int* __restrict__ counts, const int* __restrict__ partials,
                           int* __restrict__ offsets, int* __restrict__ cursors, int N) {
    int t = threadIdx.x;
    int base = blockIdx.x * (SCAN_BLOCK * SCAN_ELEMS) + t * SCAN_ELEMS;
    int c[SCAN_ELEMS];
    int s = 0;
#pragma unroll
    for (int j = 0; j < SCAN_ELEMS; ++j) {
        int i = base + j;
        c[j] = (i < N) ? counts[i] : 0;
        s += c[j];
    }
    int lane = t & 63, w = t >> 6;
    int x = s;
#pragma unroll
    for (int off = 1; off < 64; off <<= 1) { int y = __shfl_up(x, off); if (lane >= off) x += y; }
    __shared__ int lds[4];
    if (lane == 63) lds[w] = x;
    __syncthreads();
    int add = 0;
    for (int i = 0; i < w; ++i) add += lds[i];
    int run = x + add - s + partials[blockIdx.x];
#pragma unroll
    for (int j = 0; j < SCAN_ELEMS; ++j) {
        int i = base + j;
        if (i < N) { offsets[i] = run; cursors[i] = run; }
        run += c[j];
    }
}

__global__ void fill_kernel(const int* __restrict__ v_to_f, const int* __restrict__ f_to_v,
                            int* __restrict__ cursors, int* __restrict__ bucket, int V, int E) {
    int stride = gridDim.x * blockDim.x;
    for (int e = blockIdx.x * blockDim.x + threadIdx.x; e < E; e += stride) {
        int p = atomicAdd(&cursors[v_to_f[e]], 1);
        bucket[p] = e;
        int q = atomicAdd(&cursors[V + f_to_v[e]], 1);
        bucket[q] = e;
    }
}

// ================= gather-sum (segment sum, no atomics) =================

__global__ __launch_bounds__(256) void gsum_f32(
    const float* __restrict__ src, const int* __restrict__ bucket,
    const int* __restrict__ offsets, int toff,
    const float* __restrict__ addtab, float* __restrict__ sumout,
    float* __restrict__ addout, int T) {
    int gw = (int)((blockIdx.x * (long)blockDim.x + threadIdx.x) >> 6);
    if (gw >= T) return;
    int lane = threadIdx.x & 63;
    int start = offsets[toff + gw], end = offsets[toff + gw + 1];
    float ax = 0.f, ay = 0.f, bx = 0.f, by = 0.f;
    int i = start;
    for (; i + 1 < end; i += 2) {
        int e0 = bucket[i], e1 = bucket[i + 1];
        float2 v0 = *(const float2*)(src + (long)e0 * 128 + lane * 2);
        float2 v1 = *(const float2*)(src + (long)e1 * 128 + lane * 2);
        ax += v0.x; ay += v0.y; bx += v1.x; by += v1.y;
    }
    if (i < end) {
        int e0 = bucket[i];
        float2 v0 = *(const float2*)(src + (long)e0 * 128 + lane * 2);
        ax += v0.x; ay += v0.y;
    }
    ax += bx; ay += by;
    long o = (long)gw * 128 + lane * 2;
    *(float2*)(sumout + o) = make_float2(ax, ay);
    float2 a = *(const float2*)(addtab + o);
    *(float2*)(addout + o) = make_float2(ax + a.x, ay + a.y);
}

__global__ __launch_bounds__(256) void gsum_bf16(
    const __bf16* __restrict__ src, const int* __restrict__ bucket,
    const int* __restrict__ offsets, int toff,
    const float* __restrict__ addtab, float* __restrict__ sumout,
    float* __restrict__ addout, int T) {
    int gw = (int)((blockIdx.x * (long)blockDim.x + threadIdx.x) >> 6);
    if (gw >= T) return;
    int lane = threadIdx.x & 63;
    int start = offsets[toff + gw], end = offsets[toff + gw + 1];
    float ax = 0.f, ay = 0.f, bx = 0.f, by = 0.f;
    int i = start;
    for (; i + 1 < end; i += 2) {
        int e0 = bucket[i], e1 = bucket[i + 1];
        bf16x2 v0 = *(const bf16x2*)(src + (long)e0 * 128 + lane * 2);
        bf16x2 v1 = *(const bf16x2*)(src + (long)e1 * 128 + lane * 2);
        ax += (float)v0[0]; ay += (float)v0[1];
        bx += (float)v1[0]; by += (float)v1[1];
    }
    if (i < end) {
        int e0 = bucket[i];
        bf16x2 v0 = *(const bf16x2*)(src + (long)e0 * 128 + lane * 2);
        ax += (float)v0[0]; ay += (float)v0[1];
    }
    ax += bx; ay += by;
    long o = (long)gw * 128 + lane * 2;
    *(float2*)(sumout + o) = make_float2(ax, ay);
    float2 a = *(const float2*)(addtab + o);
    *(float2*)(addout + o) = make_float2(ax + a.x, ay + a.y);
}

// ================= table GEMM: G[r] = src0[r]@WA + src1[r]@WB + bias =================
// contiguous rows, K=256, bf16 output, no relu
__global__ __launch_bounds__(256, 4) void table_gemm(
    const float* __restrict__ src0, const float* __restrict__ src1,
    const __bf16* __restrict__ WT, const float* __restrict__ bias,
    __bf16* __restrict__ out, int T) {
    const int wave = threadIdx.x >> 6;
    const int lane = threadIdx.x & 63;
    const int row = lane & 15;
    const int kch = lane >> 4;
    const long wbase = ((long)blockIdx.x * 4 + wave) * 32;

    const float* p0[2]; const float* p1[2];
#pragma unroll
    for (int rb = 0; rb < 2; ++rb) {
        long r = wbase + rb * 16 + row;
        long rl = (r < T) ? r : (T - 1);
        p0[rb] = src0 + rl * 128 + kch * 8;
        p1[rb] = src1 + rl * 128 + kch * 8;
    }

    f32x4 acc[8][2];
#pragma unroll
    for (int n = 0; n < 8; ++n) {
        acc[n][0] = (f32x4){0.f, 0.f, 0.f, 0.f};
        acc[n][1] = (f32x4){0.f, 0.f, 0.f, 0.f};
    }

#pragma unroll
    for (int t = 0; t < 8; ++t) {
        bf16x8 a[2];
#pragma unroll
        for (int rb = 0; rb < 2; ++rb) {
            const float* p = (t < 4) ? (p0[rb] + t * 32) : (p1[rb] + (t - 4) * 32);
            f32x4 u0 = *(const f32x4*)p;
            f32x4 u1 = *(const f32x4*)(p + 4);
            a[rb] = pack8(u0, u1);
        }
        const __bf16* bbase = WT + (long)t * 8 * 512 + lane * 8;
#pragma unroll
        for (int n = 0; n < 8; ++n) {
            bf16x8 b = *(const bf16x8*)(bbase + n * 512);
            acc[n][0] = __builtin_amdgcn_mfma_f32_16x16x32_bf16(a[0], b, acc[n][0], 0, 0, 0);
            acc[n][1] = __builtin_amdgcn_mfma_f32_16x16x32_bf16(a[1], b, acc[n][1], 0, 0, 0);
        }
    }

    const int colbase = lane & 15;
    const int orow = (lane >> 4) * 4;
#pragma unroll
    for (int n = 0; n < 8; ++n) {
        int col = n * 16 + colbase;
        float bz = bias[col];
#pragma unroll
        for (int rb = 0; rb < 2; ++rb)
#pragma unroll
            for (int rr = 0; rr < 4; ++rr) {
                long r = wbase + rb * 16 + orow + rr;
                if (r < T) out[r * 128 + col] = (__bf16)(acc[n][rb][rr] + bz);
            }
    }
}

// ================= edge GEMM: out[e] = relu(G[idx[e]] + A0[e]@WA + eattr[e]@WB) ====
// A0 = prev_m (f32, PHASE 1) or m1 (bf16, PHASE 2).
// A staged via global_load_lds (double-buffered, XOR-swizzled source).
// Epilogue: per-wave LDS transpose -> coalesced G-gather + full-line stores.
// Block = 128 edge rows x 128 cols; wave w owns rows [w*32, w*32+32).
template <int PHASE>
__global__ __launch_bounds__(256, 4) void edge_gemm(
    const float* __restrict__ prevf, const __bf16* __restrict__ prevb,
    const float* __restrict__ eattr, const __bf16* __restrict__ WT,
    const __bf16* __restrict__ G, const int* __restrict__ idx,
    __bf16* __restrict__ outb, float* __restrict__ outf, int E) {
    __shared__ char lds[2][16384];
    const int wave = threadIdx.x >> 6;
    const int lane = threadIdx.x & 63;
    const int l16 = lane & 15;
    const int kch = lane >> 4;
    const long brow = (long)blockIdx.x * 128;

    // stage one 32-k slice (all 128 block rows) into lds[buf]
    auto stage = [&](int buf, int t) {
        char* dst = &lds[buf][0];
        if (PHASE == 2 && t < 4) {
            // bf16 source (m1): 64B/row slice, 4 chunks of 16B, 512 slots
#pragma unroll
            for (int q = 0; q < 2; ++q) {
                int s0 = q * 256 + wave * 64;        // wave-uniform slot base
                int row = (s0 >> 2) + (lane >> 2);
                int c = lane & 3;
                int c2 = c ^ ((row >> 1) & 3);       // source-side swizzle
                long rowg = brow + row; if (rowg >= E) rowg = E - 1;
                gload_lds16(prevb + rowg * 128 + t * 32 + c2 * 8, dst + s0 * 16);
            }
        } else {
            // f32 source: 128B/row slice, 8 chunks of 16B, 1024 slots
            const float* srcb = (PHASE == 1 && t < 4) ? (prevf + t * 32)
                                                      : (eattr + (t - 4) * 32);
#pragma unroll
            for (int q = 0; q < 4; ++q) {
                int s0 = q * 256 + wave * 64;
                int row = (s0 >> 3) + (lane >> 3);
                int c = lane & 7;
                int c2 = c ^ (row & 7);
                long rowg = brow + row; if (rowg >= E) rowg = E - 1;
                gload_lds16(srcb + rowg * 128 + c2 * 4, dst + s0 * 16);
            }
        }
    };

    f32x4 acc[8][2];
#pragma unroll
    for (int n = 0; n < 8; ++n) {
        acc[n][0] = (f32x4){0.f, 0.f, 0.f, 0.f};
        acc[n][1] = (f32x4){0.f, 0.f, 0.f, 0.f};
    }

    stage(0, 0);
#pragma unroll
    for (int t = 0; t < 8; ++t) {
        __syncthreads();                 // drains last iter's stage (incl. vmcnt)
        if (t < 7) stage((t + 1) & 1, t + 1);  // flies during compute below
        const char* cur = &lds[t & 1][0];
        bf16x8 a[2];
#pragma unroll
        for (int rb = 0; rb < 2; ++rb) {
            int row = wave * 32 + rb * 16 + l16;
            if (PHASE == 2 && t < 4) {
                int off = row * 64 + ((kch ^ ((row >> 1) & 3)) * 16);
                a[rb] = *(const bf16x8*)(cur + off);
            } else {
                int base = row * 128;
                int s0 = (((kch * 2 + 0) ^ (row & 7)) * 16);
                int s1 = (((kch * 2 + 1) ^ (row & 7)) * 16);
                f32x4 u0 = *(const f32x4*)(cur + base + s0);
                f32x4 u1 = *(const f32x4*)(cur + base + s1);
                a[rb] = pack8(u0, u1);
            }
        }
        const __bf16* bbase = WT + (long)t * 8 * 512 + lane * 8;
#pragma unroll
        for (int n = 0; n < 8; ++n) {
            bf16x8 b = *(const bf16x8*)(bbase + n * 512);
            acc[n][0] = __builtin_amdgcn_mfma_f32_16x16x32_bf16(a[0], b, acc[n][0], 0, 0, 0);
            acc[n][1] = __builtin_amdgcn_mfma_f32_16x16x32_bf16(a[1], b, acc[n][1], 0, 0, 0);
        }
    }

    // ---- epilogue: per-wave LDS transpose -> coalesced G-add + stores ----
    __syncthreads();   // all waves done reading staging buffers
    float* lbuf = (float*)((char*)lds + wave * 8192);  // [16][128] f32, slot-swizzled
    const int slotcol = lane & 31;    // 16B slot within a 512B row
    const int rhalf = lane >> 5;      // 0..1
#pragma unroll
    for (int rb = 0; rb < 2; ++rb) {
        // scatter acc into LDS (XOR slot swizzle; 2-way banks max)
#pragma unroll
        for (int n = 0; n < 8; ++n)
#pragma unroll
            for (int rr = 0; rr < 4; ++rr) {
                int row = kch * 4 + rr;
                int col = n * 16 + l16;
                int slot = col >> 2;
                lbuf[row * 128 + (((slot ^ (row & 7)) << 2) | (col & 3))] = acc[n][rb][rr];
            }
        // read back row-major; 32 lanes cover one full 512B row
#pragma unroll
        for (int j = 0; j < 8; ++j) {
            int row = 2 * j + rhalf;
            long eo = brow + wave * 32 + rb * 16 + row;
            f32x4 v = *(const f32x4*)&lbuf[row * 128 + ((slotcol ^ (row & 7)) << 2)];
            if (eo < E) {
                int g = idx[eo];
                bf16x4 gb = *(const bf16x4*)(G + (long)g * 128 + slotcol * 4);
                f32x4 o;
#pragma unroll
                for (int i = 0; i < 4; ++i) {
                    float x = v[i] + (float)gb[i];
                    o[i] = x > 0.f ? x : 0.f;
                }
                if (PHASE == 1) {
                    bf16x4 ob;
#pragma unroll
                    for (int i = 0; i < 4; ++i) ob[i] = (__bf16)o[i];
                    *(bf16x4*)(outb + eo * 128 + slotcol * 4) = ob;
                } else {
                    *(f32x4*)(outf + eo * 128 + slotcol * 4) = o;
                }
            }
        }
    }
}

extern "C" void kernel_launch(void* const* d_in, const int* in_sizes, int n_in,
                              void* d_out, int out_size, void* d_ws, size_t ws_size,
                              hipStream_t stream) {
    const float* prev_m   = (const float*)d_in[0];
    const float* variable = (const float*)d_in[1];
    const float* factor   = (const float*)d_in[2];
    const float* eattr    = (const float*)d_in[3];
    const int*   v_to_f   = (const int*)d_in[4];
    const int*   f_to_v   = (const int*)d_in[5];
    const float* Wv       = (const float*)d_in[6];
    const float* bv       = (const float*)d_in[7];
    const float* Wf       = (const float*)d_in[8];
    const float* bf       = (const float*)d_in[9];

    const int E = in_sizes[0] / 128;
    const int V = in_sizes[1] / 128;
    const int F = in_sizes[2] / 128;
    const int NT = V + F;

    float* out_m        = (float*)d_out;               // [E,128]
    float* out_factor   = out_m + (long)E * 128;       // [F,128]
    float* out_variable = out_factor + (long)F * 128;  // [V,128]

    char* ws = (char*)d_ws;
    float* sum_f_to_v = (float*)ws;  ws += (long)V * 128 * 4;
    float* sum_v_to_f = (float*)ws;  ws += (long)F * 128 * 4;
    __bf16* m1        = (__bf16*)ws; ws += (long)E * 128 * 2;
    __bf16* G1        = (__bf16*)ws; ws += (long)V * 128 * 2;
    __bf16* G2        = (__bf16*)ws; ws += (long)F * 128 * 2;
    __bf16* Wtab_v    = (__bf16*)ws; ws += 256 * 128 * 2;
    __bf16* Wedge_v   = (__bf16*)ws; ws += 256 * 128 * 2;
    __bf16* Wtab_f    = (__bf16*)ws; ws += 256 * 128 * 2;
    __bf16* Wedge_f   = (__bf16*)ws; ws += 256 * 128 * 2;
    int* counts       = (int*)ws;    ws += (long)NT * 4;
    int* offsets      = (int*)ws;    ws += (long)(NT + 1) * 4;
    int* cursors      = (int*)ws;    ws += (long)NT * 4;
    int* bucket       = (int*)ws;    ws += (long)2 * E * 4;
    int* partials     = (int*)ws;    ws += 256 * 4;

    hipMemsetAsync(counts, 0, (size_t)NT * 4, stream);

    // weight packs: table = [W1; W2], edge = [-W2; W3]
    pack_w<<<dim3(128), dim3(256), 0, stream>>>(Wv, Wtab_v,  0,   1.f, 128, 1.f);
    pack_w<<<dim3(128), dim3(256), 0, stream>>>(Wv, Wedge_v, 128, -1.f, 256, 1.f);
    pack_w<<<dim3(128), dim3(256), 0, stream>>>(Wf, Wtab_f,  0,   1.f, 128, 1.f);
    pack_w<<<dim3(128), dim3(256), 0, stream>>>(Wf, Wedge_f, 128, -1.f, 256, 1.f);

    // ---- CSR build ----
    hist_kernel<<<dim3(2048), dim3(256), 0, stream>>>(v_to_f, f_to_v, counts, V, E);
    int nb = (NT + SCAN_BLOCK * SCAN_ELEMS - 1) / (SCAN_BLOCK * SCAN_ELEMS);  // 147 <= 256
    scan_pass1<<<dim3(nb), dim3(SCAN_BLOCK), 0, stream>>>(counts, partials, NT);
    scan_pass2<<<dim3(1), dim3(SCAN_BLOCK), 0, stream>>>(partials, nb, offsets, NT, 2 * E);
    scan_pass3<<<dim3(nb), dim3(SCAN_BLOCK), 0, stream>>>(counts, partials, offsets, cursors, NT);
    fill_kernel<<<dim3(2048), dim3(256), 0, stream>>>(v_to_f, f_to_v, cursors, bucket, V, E);

    // ---- sum_f_to_v = segsum(prev_m); new_variable = sum + variable ----
    gsum_f32<<<dim3((V + 3) / 4), dim3(256), 0, stream>>>(
        prev_m, bucket, offsets, 0, variable, sum_f_to_v, out_variable, V);

    // ---- G1[v] = var@Wv1 + sum@Wv2 + bv ----
    table_gemm<<<dim3((V + 127) / 128), dim3(256), 0, stream>>>(
        variable, sum_f_to_v, Wtab_v, bv, G1, V);

    // ---- m1 = relu(G1[v[e]] - prev@Wv2 + eattr@Wv3) ----
    int eblocks = (E + 127) / 128;
    edge_gemm<1><<<dim3(eblocks), dim3(256), 0, stream>>>(
        prev_m, nullptr, eattr, Wedge_v, G1, v_to_f, m1, nullptr, E);

    // ---- sum_v_to_f = segsum(m1); new_factor = sum + factor ----
    gsum_bf16<<<dim3((F + 3) / 4), dim3(256), 0, stream>>>(
        m1, bucket, offsets, V, factor, sum_v_to_f, out_factor, F);

    // ---- G2[f] = factor@Wf1 + sum@Wf2 + bf ----
    table_gemm<<<dim3((F + 127) / 128), dim3(256), 0, stream>>>(
        factor, sum_v_to_f, Wtab_f, bf, G2, F);

    // ---- out_m = relu(G2[f[e]] - m1@Wf2 + eattr@Wf3) ----
    edge_gemm<2><<<dim3(eblocks), dim3(256), 0, stream>>>(
        nullptr, m1, eattr, Wedge_f, G2, f_to_v, nullptr, out_m, E);
}

// Round 7
// 713.384 us; speedup vs baseline: 2.4719x; 1.0065x over previous
//
#include <hip/hip_runtime.h>

typedef __attribute__((ext_vector_type(8))) __bf16 bf16x8;
typedef __attribute__((ext_vector_type(4))) __bf16 bf16x4;
typedef __attribute__((ext_vector_type(2))) __bf16 bf16x2;
typedef __attribute__((ext_vector_type(4))) float f32x4;

template <int N> struct ic { static constexpr int value = N; };

__device__ __forceinline__ void gload_lds16(const void* g, void* l) {
    __builtin_amdgcn_global_load_lds(
        (const __attribute__((address_space(1))) void*)g,
        (__attribute__((address_space(3))) void*)l, 16, 0, 0);
}

__device__ inline bf16x8 pack8(f32x4 u0, f32x4 u1) {
    bf16x8 r;
    r[0] = (__bf16)u0[0]; r[1] = (__bf16)u0[1]; r[2] = (__bf16)u0[2]; r[3] = (__bf16)u0[3];
    r[4] = (__bf16)u1[0]; r[5] = (__bf16)u1[1]; r[6] = (__bf16)u1[2]; r[7] = (__bf16)u1[3];
    return r;
}

// ---- pack all 4 weight blocks into MFMA B-fragment order (one launch) ----
// table = [W1; W2] (sgn +,+), edge = [-W2; W3]
__global__ void pack_all(const float* __restrict__ Wv, const float* __restrict__ Wf,
                         __bf16* __restrict__ Wtab_v, __bf16* __restrict__ Wedge_v,
                         __bf16* __restrict__ Wtab_f, __bf16* __restrict__ Wedge_f) {
    int which = blockIdx.x >> 7;                       // 0..3
    int i = ((blockIdx.x & 127) << 8) + threadIdx.x;   // 0..32767
    const float* W = (which < 2) ? Wv : Wf;
    __bf16* out = (which == 0) ? Wtab_v : (which == 1) ? Wedge_v
                 : (which == 2) ? Wtab_f : Wedge_f;
    int baseA = (which & 1) ? 128 : 0;
    float sA  = (which & 1) ? -1.f : 1.f;
    int baseB = (which & 1) ? 256 : 128;
    int k = i >> 7, d = i & 127;
    float v = (k < 128) ? sA * W[(long)(baseA + k) * 128 + d]
                        : W[(long)(baseB + (k - 128)) * 128 + d];
    int t = k >> 5, n = d >> 4;
    int lane = (d & 15) | (((k >> 3) & 3) << 4);
    int j = k & 7;
    out[((long)(t * 8 + n) * 64 + lane) * 8 + j] = (__bf16)v;
}

// ================= CSR build (counts -> scan -> fill) =================

__global__ void hist_kernel(const int* __restrict__ v_to_f, const int* __restrict__ f_to_v,
                            int* __restrict__ counts, int V, int E) {
    int stride = gridDim.x * blockDim.x;
    for (int e = blockIdx.x * blockDim.x + threadIdx.x; e < E; e += stride) {
        atomicAdd(&counts[v_to_f[e]], 1);
        atomicAdd(&counts[V + f_to_v[e]], 1);
    }
}

#define SCAN_BLOCK 256
#define SCAN_ELEMS 4   // 1024 elements per block

__global__ void scan_pass1(const int* __restrict__ counts, int* __restrict__ partials, int N) {
    int t = threadIdx.x;
    int base = blockIdx.x * (SCAN_BLOCK * SCAN_ELEMS) + t * SCAN_ELEMS;
    int s = 0;
#pragma unroll
    for (int j = 0; j < SCAN_ELEMS; ++j) {
        int i = base + j;
        if (i < N) s += counts[i];
    }
#pragma unroll
    for (int off = 1; off < 64; off <<= 1) s += __shfl_xor(s, off);
    __shared__ int lds[4];
    if ((t & 63) == 0) lds[t >> 6] = s;
    __syncthreads();
    if (t == 0) partials[blockIdx.x] = lds[0] + lds[1] + lds[2] + lds[3];
}

// pass2 folded in: each block redundantly prefixes partials[0..bid)
__global__ void scan_pass3(const int* __restrict__ counts, const int* __restrict__ partials,
                           int* __restrict__ offsets, int* __restrict__ cursors,
                           int N, int total) {
    int t = threadIdx.x;
    int pre = 0;
    for (int i = 0; i < (int)blockIdx.x; ++i) pre += partials[i];
    int base = blockIdx.x * (SCAN_BLOCK * SCAN_ELEMS) + t * SCAN_ELEMS;
    int c[SCAN_ELEMS];
    int s = 0;
#pragma unroll
    for (int j = 0; j < SCAN_ELEMS; ++j) {
        int i = base + j;
        c[j] = (i < N) ? counts[i] : 0;
        s += c[j];
    }
    int lane = t & 63, w = t >> 6;
    int x = s;
#pragma unroll
    for (int off = 1; off < 64; off <<= 1) { int y = __shfl_up(x, off); if (lane >= off) x += y; }
    __shared__ int lds[4];
    if (lane == 63) lds[w] = x;
    __syncthreads();
    int add = 0;
    for (int i = 0; i < w; ++i) add += lds[i];
    int run = x + add - s + pre;
#pragma unroll
    for (int j = 0; j < SCAN_ELEMS; ++j) {
        int i = base + j;
        if (i < N) { offsets[i] = run; cursors[i] = run; }
        run += c[j];
    }
    if (blockIdx.x == 0 && t == 0) offsets[N] = total;
}

__global__ void fill_kernel(const int* __restrict__ v_to_f, const int* __restrict__ f_to_v,
                            int* __restrict__ cursors, int* __restrict__ bucket, int V, int E) {
    int stride = gridDim.x * blockDim.x;
    for (int e = blockIdx.x * blockDim.x + threadIdx.x; e < E; e += stride) {
        int p = atomicAdd(&cursors[v_to_f[e]], 1);
        bucket[p] = e;
        int q = atomicAdd(&cursors[V + f_to_v[e]], 1);
        bucket[q] = e;
    }
}

// ================= gather-sum (segment sum, no atomics, unroll-4) =================

__global__ __launch_bounds__(256) void gsum_f32(
    const float* __restrict__ src, const int* __restrict__ bucket,
    const int* __restrict__ offsets, int toff,
    const float* __restrict__ addtab, float* __restrict__ sumout,
    float* __restrict__ addout, int T) {
    int gw = (int)((blockIdx.x * (long)blockDim.x + threadIdx.x) >> 6);
    if (gw >= T) return;
    int lane = threadIdx.x & 63;
    int start = offsets[toff + gw], end = offsets[toff + gw + 1];
    float ax = 0.f, ay = 0.f, bx = 0.f, by = 0.f;
    float cx = 0.f, cy = 0.f, dx = 0.f, dy = 0.f;
    int i = start;
    for (; i + 3 < end; i += 4) {
        int e0 = bucket[i], e1 = bucket[i + 1], e2 = bucket[i + 2], e3 = bucket[i + 3];
        float2 v0 = *(const float2*)(src + (long)e0 * 128 + lane * 2);
        float2 v1 = *(const float2*)(src + (long)e1 * 128 + lane * 2);
        float2 v2 = *(const float2*)(src + (long)e2 * 128 + lane * 2);
        float2 v3 = *(const float2*)(src + (long)e3 * 128 + lane * 2);
        ax += v0.x; ay += v0.y; bx += v1.x; by += v1.y;
        cx += v2.x; cy += v2.y; dx += v3.x; dy += v3.y;
    }
    for (; i < end; ++i) {
        int e0 = bucket[i];
        float2 v0 = *(const float2*)(src + (long)e0 * 128 + lane * 2);
        ax += v0.x; ay += v0.y;
    }
    ax += bx + cx + dx; ay += by + cy + dy;
    long o = (long)gw * 128 + lane * 2;
    *(float2*)(sumout + o) = make_float2(ax, ay);
    float2 a = *(const float2*)(addtab + o);
    *(float2*)(addout + o) = make_float2(ax + a.x, ay + a.y);
}

__global__ __launch_bounds__(256) void gsum_bf16(
    const __bf16* __restrict__ src, const int* __restrict__ bucket,
    const int* __restrict__ offsets, int toff,
    const float* __restrict__ addtab, float* __restrict__ sumout,
    float* __restrict__ addout, int T) {
    int gw = (int)((blockIdx.x * (long)blockDim.x + threadIdx.x) >> 6);
    if (gw >= T) return;
    int lane = threadIdx.x & 63;
    int start = offsets[toff + gw], end = offsets[toff + gw + 1];
    float ax = 0.f, ay = 0.f, bx = 0.f, by = 0.f;
    float cx = 0.f, cy = 0.f, dx = 0.f, dy = 0.f;
    int i = start;
    for (; i + 3 < end; i += 4) {
        int e0 = bucket[i], e1 = bucket[i + 1], e2 = bucket[i + 2], e3 = bucket[i + 3];
        bf16x2 v0 = *(const bf16x2*)(src + (long)e0 * 128 + lane * 2);
        bf16x2 v1 = *(const bf16x2*)(src + (long)e1 * 128 + lane * 2);
        bf16x2 v2 = *(const bf16x2*)(src + (long)e2 * 128 + lane * 2);
        bf16x2 v3 = *(const bf16x2*)(src + (long)e3 * 128 + lane * 2);
        ax += (float)v0[0]; ay += (float)v0[1]; bx += (float)v1[0]; by += (float)v1[1];
        cx += (float)v2[0]; cy += (float)v2[1]; dx += (float)v3[0]; dy += (float)v3[1];
    }
    for (; i < end; ++i) {
        int e0 = bucket[i];
        bf16x2 v0 = *(const bf16x2*)(src + (long)e0 * 128 + lane * 2);
        ax += (float)v0[0]; ay += (float)v0[1];
    }
    ax += bx + cx + dx; ay += by + cy + dy;
    long o = (long)gw * 128 + lane * 2;
    *(float2*)(sumout + o) = make_float2(ax, ay);
    float2 a = *(const float2*)(addtab + o);
    *(float2*)(addout + o) = make_float2(ax + a.x, ay + a.y);
}

// ================= table GEMM: G[r] = src0[r]@WA + src1[r]@WB + bias =================
__global__ __launch_bounds__(256, 4) void table_gemm(
    const float* __restrict__ src0, const float* __restrict__ src1,
    const __bf16* __restrict__ WT, const float* __restrict__ bias,
    __bf16* __restrict__ out, int T) {
    const int wave = threadIdx.x >> 6;
    const int lane = threadIdx.x & 63;
    const int row = lane & 15;
    const int kch = lane >> 4;
    const long wbase = ((long)blockIdx.x * 4 + wave) * 32;

    const float* p0[2]; const float* p1[2];
#pragma unroll
    for (int rb = 0; rb < 2; ++rb) {
        long r = wbase + rb * 16 + row;
        long rl = (r < T) ? r : (T - 1);
        p0[rb] = src0 + rl * 128 + kch * 8;
        p1[rb] = src1 + rl * 128 + kch * 8;
    }

    f32x4 acc[8][2];
#pragma unroll
    for (int n = 0; n < 8; ++n) {
        acc[n][0] = (f32x4){0.f, 0.f, 0.f, 0.f};
        acc[n][1] = (f32x4){0.f, 0.f, 0.f, 0.f};
    }

#pragma unroll
    for (int t = 0; t < 8; ++t) {
        bf16x8 a[2];
#pragma unroll
        for (int rb = 0; rb < 2; ++rb) {
            const float* p = (t < 4) ? (p0[rb] + t * 32) : (p1[rb] + (t - 4) * 32);
            f32x4 u0 = *(const f32x4*)p;
            f32x4 u1 = *(const f32x4*)(p + 4);
            a[rb] = pack8(u0, u1);
        }
        const __bf16* bbase = WT + (long)t * 8 * 512 + lane * 8;
#pragma unroll
        for (int n = 0; n < 8; ++n) {
            bf16x8 b = *(const bf16x8*)(bbase + n * 512);
            acc[n][0] = __builtin_amdgcn_mfma_f32_16x16x32_bf16(a[0], b, acc[n][0], 0, 0, 0);
            acc[n][1] = __builtin_amdgcn_mfma_f32_16x16x32_bf16(a[1], b, acc[n][1], 0, 0, 0);
        }
    }

    const int colbase = lane & 15;
    const int orow = (lane >> 4) * 4;
#pragma unroll
    for (int n = 0; n < 8; ++n) {
        int col = n * 16 + colbase;
        float bz = bias[col];
#pragma unroll
        for (int rb = 0; rb < 2; ++rb)
#pragma unroll
            for (int rr = 0; rr < 4; ++rr) {
                long r = wbase + rb * 16 + orow + rr;
                if (r < T) out[r * 128 + col] = (__bf16)(acc[n][rb][rr] + bz);
            }
    }
}

// ================= edge GEMM: out[e] = relu(G[idx[e]] + A0[e]@WA + eattr[e]@WB) ====
// Per-wave barrier-free pipeline: wave owns 32 rows; 3 rotating 4KB LDS slots;
// stage issued 2 iters ahead via global_load_lds; B-frags reg-pipelined 1 iter
// ahead, issued BEFORE the stage so counted-vmcnt retirement never drains depth.
template <int PHASE>
__global__ __launch_bounds__(256, 3) void edge_gemm(
    const float* __restrict__ prevf, const __bf16* __restrict__ prevb,
    const float* __restrict__ eattr, const __bf16* __restrict__ WT,
    const __bf16* __restrict__ G, const int* __restrict__ idx,
    __bf16* __restrict__ outb, float* __restrict__ outf, int E) {
    __shared__ char lds[4][12288];
    const int wave = threadIdx.x >> 6;
    const int lane = threadIdx.x & 63;
    const int l16 = lane & 15;
    const int kch = lane >> 4;
    const long brow = (long)blockIdx.x * 128;
    const long wrow = brow + wave * 32;
    char* wls = &lds[wave][0];

    bf16x8 bufA[8], bufB[8];
    f32x4 acc[8][2];
#pragma unroll
    for (int n = 0; n < 8; ++n) {
        acc[n][0] = (f32x4){0.f, 0.f, 0.f, 0.f};
        acc[n][1] = (f32x4){0.f, 0.f, 0.f, 0.f};
    }

    // stage one 32-k slice of this wave's 32 rows into slot S%3
    auto stage = [&](auto tcS) {
        constexpr int S = decltype(tcS)::value;
        char* dst = wls + (S % 3) * 4096;
        if constexpr (PHASE == 2 && S < 4) {
            // bf16 m1: 32 rows x 64B = 2 x 1KB issues
#pragma unroll
            for (int q = 0; q < 2; ++q) {
                int row = q * 16 + (lane >> 2);
                int c2 = (lane & 3) ^ ((row >> 1) & 3);
                long rg = wrow + row; if (rg >= E) rg = E - 1;
                gload_lds16(prevb + rg * 128 + S * 32 + c2 * 8, dst + q * 1024);
            }
        } else {
            const float* srcb = (PHASE == 1 && S < 4) ? (prevf + S * 32)
                                                      : (eattr + (S - 4) * 32);
#pragma unroll
            for (int q = 0; q < 4; ++q) {
                int row = q * 8 + (lane >> 3);
                int c2 = (lane & 7) ^ (row & 7);
                long rg = wrow + row; if (rg >= E) rg = E - 1;
                gload_lds16(srcb + rg * 128 + c2 * 4, dst + q * 1024);
            }
        }
    };

    auto loadB = [&](auto tcT, bf16x8* bn) {
        constexpr int T = decltype(tcT)::value;
        const __bf16* bb = WT + (long)T * 4096 + lane * 8;
#pragma unroll
        for (int n = 0; n < 8; ++n) bn[n] = *(const bf16x8*)(bb + n * 512);
    };

    // prologue: S0, B0, S1 (order matters for vmcnt retirement)
    stage(ic<0>{});
    __builtin_amdgcn_sched_barrier(0);
    loadB(ic<0>{}, bufA);
    __builtin_amdgcn_sched_barrier(0);
    stage(ic<1>{});
    __builtin_amdgcn_sched_barrier(0);

    auto iter = [&](auto tcT) {
        constexpr int T = decltype(tcT)::value;
        // newer-than-S(T) at this point: B(T)=8 + S(T+1)=L(T+1)
        constexpr int NS = (T < 7) ? (8 + ((PHASE == 2 && (T + 1) < 4) ? 2 : 4)) : 8;
        asm volatile("s_waitcnt vmcnt(%0)" :: "n"(NS) : "memory");
        __builtin_amdgcn_sched_barrier(0);
        // issue next B (must precede next stage), then next stage
        if constexpr (T < 7) loadB(ic<T + 1>{}, (T & 1) ? bufA : bufB);
        __builtin_amdgcn_sched_barrier(0);
        if constexpr (T < 6) stage(ic<T + 2>{});
        __builtin_amdgcn_sched_barrier(0);
        // ds_read A from slot T%3
        const char* cur = wls + (T % 3) * 4096;
        bf16x8 a[2];
#pragma unroll
        for (int rb = 0; rb < 2; ++rb) {
            int row = rb * 16 + l16;
            if constexpr (PHASE == 2 && T < 4) {
                a[rb] = *(const bf16x8*)(cur + row * 64 + ((kch ^ ((row >> 1) & 3)) * 16));
            } else {
                f32x4 u0 = *(const f32x4*)(cur + row * 128 + (((kch * 2) ^ (row & 7)) * 16));
                f32x4 u1 = *(const f32x4*)(cur + row * 128 + (((kch * 2 + 1) ^ (row & 7)) * 16));
                a[rb] = pack8(u0, u1);
            }
        }
        bf16x8* bc = (T & 1) ? bufB : bufA;
#pragma unroll
        for (int n = 0; n < 8; ++n) {
            acc[n][0] = __builtin_amdgcn_mfma_f32_16x16x32_bf16(a[0], bc[n], acc[n][0], 0, 0, 0);
            acc[n][1] = __builtin_amdgcn_mfma_f32_16x16x32_bf16(a[1], bc[n], acc[n][1], 0, 0, 0);
        }
    };
    iter(ic<0>{}); iter(ic<1>{}); iter(ic<2>{}); iter(ic<3>{});
    iter(ic<4>{}); iter(ic<5>{}); iter(ic<6>{}); iter(ic<7>{});

    // ---- epilogue: wave-private LDS transpose -> coalesced G-add + stores ----
    float* lbuf = (float*)wls;        // [16][128] f32, slot-swizzled (8KB < 12KB)
    const int slotcol = lane & 31;
    const int rhalf = lane >> 5;
#pragma unroll
    for (int rb = 0; rb < 2; ++rb) {
#pragma unroll
        for (int n = 0; n < 8; ++n)
#pragma unroll
            for (int rr = 0; rr < 4; ++rr) {
                int row = kch * 4 + rr;
                int col = n * 16 + l16;
                int slot = col >> 2;
                lbuf[row * 128 + (((slot ^ (row & 7)) << 2) | (col & 3))] = acc[n][rb][rr];
            }
#pragma unroll
        for (int j = 0; j < 8; ++j) {
            int row = 2 * j + rhalf;
            long eo = wrow + rb * 16 + row;
            f32x4 v = *(const f32x4*)&lbuf[row * 128 + ((slotcol ^ (row & 7)) << 2)];
            if (eo < E) {
                int g = idx[eo];
                bf16x4 gb = *(const bf16x4*)(G + (long)g * 128 + slotcol * 4);
                f32x4 o;
#pragma unroll
                for (int i = 0; i < 4; ++i) {
                    float x = v[i] + (float)gb[i];
                    o[i] = x > 0.f ? x : 0.f;
                }
                if (PHASE == 1) {
                    bf16x4 ob;
#pragma unroll
                    for (int i = 0; i < 4; ++i) ob[i] = (__bf16)o[i];
                    *(bf16x4*)(outb + eo * 128 + slotcol * 4) = ob;
                } else {
                    *(f32x4*)(outf + eo * 128 + slotcol * 4) = o;
                }
            }
        }
    }
}

extern "C" void kernel_launch(void* const* d_in, const int* in_sizes, int n_in,
                              void* d_out, int out_size, void* d_ws, size_t ws_size,
                              hipStream_t stream) {
    const float* prev_m   = (const float*)d_in[0];
    const float* variable = (const float*)d_in[1];
    const float* factor   = (const float*)d_in[2];
    const float* eattr    = (const float*)d_in[3];
    const int*   v_to_f   = (const int*)d_in[4];
    const int*   f_to_v   = (const int*)d_in[5];
    const float* Wv       = (const float*)d_in[6];
    const float* bv       = (const float*)d_in[7];
    const float* Wf       = (const float*)d_in[8];
    const float* bf       = (const float*)d_in[9];

    const int E = in_sizes[0] / 128;
    const int V = in_sizes[1] / 128;
    const int F = in_sizes[2] / 128;
    const int NT = V + F;

    float* out_m        = (float*)d_out;               // [E,128]
    float* out_factor   = out_m + (long)E * 128;       // [F,128]
    float* out_variable = out_factor + (long)F * 128;  // [V,128]

    char* ws = (char*)d_ws;
    float* sum_f_to_v = (float*)ws;  ws += (long)V * 128 * 4;
    float* sum_v_to_f = (float*)ws;  ws += (long)F * 128 * 4;
    __bf16* m1        = (__bf16*)ws; ws += (long)E * 128 * 2;
    __bf16* G1        = (__bf16*)ws; ws += (long)V * 128 * 2;
    __bf16* G2        = (__bf16*)ws; ws += (long)F * 128 * 2;
    __bf16* Wtab_v    = (__bf16*)ws; ws += 256 * 128 * 2;
    __bf16* Wedge_v   = (__bf16*)ws; ws += 256 * 128 * 2;
    __bf16* Wtab_f    = (__bf16*)ws; ws += 256 * 128 * 2;
    __bf16* Wedge_f   = (__bf16*)ws; ws += 256 * 128 * 2;
    int* counts       = (int*)ws;    ws += (long)NT * 4;
    int* offsets      = (int*)ws;    ws += (long)(NT + 1) * 4;
    int* cursors      = (int*)ws;    ws += (long)NT * 4;
    int* bucket       = (int*)ws;    ws += (long)2 * E * 4;
    int* partials     = (int*)ws;    ws += 256 * 4;

    hipMemsetAsync(counts, 0, (size_t)NT * 4, stream);

    pack_all<<<dim3(512), dim3(256), 0, stream>>>(Wv, Wf, Wtab_v, Wedge_v, Wtab_f, Wedge_f);

    // ---- CSR build ----
    hist_kernel<<<dim3(2048), dim3(256), 0, stream>>>(v_to_f, f_to_v, counts, V, E);
    int nb = (NT + SCAN_BLOCK * SCAN_ELEMS - 1) / (SCAN_BLOCK * SCAN_ELEMS);  // 147
    scan_pass1<<<dim3(nb), dim3(SCAN_BLOCK), 0, stream>>>(counts, partials, NT);
    scan_pass3<<<dim3(nb), dim3(SCAN_BLOCK), 0, stream>>>(counts, partials, offsets, cursors,
                                                          NT, 2 * E);
    fill_kernel<<<dim3(2048), dim3(256), 0, stream>>>(v_to_f, f_to_v, cursors, bucket, V, E);

    // ---- sum_f_to_v = segsum(prev_m); new_variable = sum + variable ----
    gsum_f32<<<dim3((V + 3) / 4), dim3(256), 0, stream>>>(
        prev_m, bucket, offsets, 0, variable, sum_f_to_v, out_variable, V);

    // ---- G1[v] = var@Wv1 + sum@Wv2 + bv ----
    table_gemm<<<dim3((V + 127) / 128), dim3(256), 0, stream>>>(
        variable, sum_f_to_v, Wtab_v, bv, G1, V);

    // ---- m1 = relu(G1[v[e]] - prev@Wv2 + eattr@Wv3) ----
    int eblocks = (E + 127) / 128;
    edge_gemm<1><<<dim3(eblocks), dim3(256), 0, stream>>>(
        prev_m, nullptr, eattr, Wedge_v, G1, v_to_f, m1, nullptr, E);

    // ---- sum_v_to_f = segsum(m1); new_factor = sum + factor ----
    gsum_bf16<<<dim3((F + 3) / 4), dim3(256), 0, stream>>>(
        m1, bucket, offsets, V, factor, sum_v_to_f, out_factor, F);

    // ---- G2[f] = factor@Wf1 + sum@Wf2 + bf ----
    table_gemm<<<dim3((F + 127) / 128), dim3(256), 0, stream>>>(
        factor, sum_v_to_f, Wtab_f, bf, G2, F);

    // ---- out_m = relu(G2[f[e]] - m1@Wf2 + eattr@Wf3) ----
    edge_gemm<2><<<dim3(eblocks), dim3(256), 0, stream>>>(
        nullptr, m1, eattr, Wedge_f, G2, f_to_v, nullptr, out_m, E);
}